// Round 1
// baseline (539.174 us; speedup 1.0000x reference)
//
#include <hip/hip_runtime.h>
#include <math.h>

#define Bq   2048
#define Cq   8
#define Dq   768
#define NROW 16384      // B*C per half
#define NTOT 32768      // 2*B*C
#define Nq   4096       // 2*B rows of f
#define TEMPq 0.07f
#define NBIN 4096

// persistent device scratch (fully overwritten every call -> deterministic)
__device__ float g_scores[NTOT];
__device__ float g_max2[2];
__device__ float g_pooled[(size_t)Nq * Dq];
__device__ float g_f[(size_t)Nq * Dq];
__device__ float g_sim[(size_t)Nq * Nq];
__device__ int   g_counts[Nq];
__device__ float g_rowmax[Nq];
__device__ float g_pos[Nq];
__device__ int   g_kk;
__device__ float g_rowloss[Nq];

// ---------- scores = (z @ query) / t, one wave per row ----------
__global__ __launch_bounds__(256) void scores_kernel(const float* __restrict__ z,
                                                     const float* __restrict__ query,
                                                     const float* __restrict__ attn_temp) {
    int wave = (int)((blockIdx.x * blockDim.x + threadIdx.x) >> 6);
    int lane = threadIdx.x & 63;
    if (wave >= NTOT) return;
    const float* zr = z + (size_t)wave * Dq;
    float s = 0.f;
#pragma unroll
    for (int j = 0; j < Dq / 64; ++j) s += zr[j * 64 + lane] * query[j * 64 + lane];
#pragma unroll
    for (int o = 32; o > 0; o >>= 1) s += __shfl_xor(s, o, 64);
    if (lane == 0) g_scores[wave] = s / attn_temp[0];
}

// ---------- per-half max of scores ----------
__global__ __launch_bounds__(256) void max_kernel() {
    int half = blockIdx.x;
    const float* s = g_scores + half * NROW;
    float m = -1e30f;
    for (int i = threadIdx.x; i < NROW; i += 256) m = fmaxf(m, s[i]);
    __shared__ float sm[256];
    sm[threadIdx.x] = m; __syncthreads();
    for (int o = 128; o > 0; o >>= 1) {
        if (threadIdx.x < o) sm[threadIdx.x] = fmaxf(sm[threadIdx.x], sm[threadIdx.x + o]);
        __syncthreads();
    }
    if (threadIdx.x == 0) g_max2[half] = sm[0];
}

// ---------- attention pooling: one wave per segment of 8 rows ----------
__global__ __launch_bounds__(256) void pool_kernel(const float* __restrict__ z) {
    int seg  = (int)((blockIdx.x * blockDim.x + threadIdx.x) >> 6);
    int lane = threadIdx.x & 63;
    if (seg >= Nq) return;
    int half = seg >> 11;          // 0 = ori, 1 = aug
    int b    = seg & 2047;
    int baseRow = half * NROW + b * Cq;
    float gmax = g_max2[half];
    float e[Cq];
    float denom = 0.f;
#pragma unroll
    for (int c = 0; c < Cq; ++c) { e[c] = expf(g_scores[baseRow + c] - gmax); denom += e[c]; }
    float inv = 1.f / (denom + 1e-8f);
#pragma unroll
    for (int j = 0; j < Dq / 64; ++j) {
        int col = j * 64 + lane;
        float acc = 0.f;
#pragma unroll
        for (int c = 0; c < Cq; ++c) acc += z[(size_t)(baseRow + c) * Dq + col] * e[c];
        g_pooled[(size_t)seg * Dq + col] = acc * inv;
    }
}

// ---------- generic fp32 GEMM: C[M x Nn] = A(M x 768) * Bt(Nn x 768)^T (+bias) ----------
__device__ __forceinline__ void gemm_body(const float* __restrict__ A,
                                          const float* __restrict__ Bt,
                                          const float* __restrict__ bias,
                                          float* __restrict__ Cc, int Nn, int withBias) {
    __shared__ float As[8][128];
    __shared__ float Bs[8][128];
    const int tid = threadIdx.x;
    const int tx = tid & 15;    // 16
    const int ty = tid >> 4;    // 16
    const int bm = blockIdx.y * 128;
    const int bn = blockIdx.x * 128;
    float acc[8][8];
#pragma unroll
    for (int i = 0; i < 8; ++i)
#pragma unroll
        for (int j = 0; j < 8; ++j) acc[i][j] = 0.f;

    const int lr = tid >> 1;         // tile row 0..127
    const int lc = (tid & 1) * 4;    // k sub-offset 0 or 4

    for (int k0 = 0; k0 < Dq; k0 += 8) {
        float4 va = *(const float4*)(A  + (size_t)(bm + lr) * Dq + k0 + lc);
        float4 vb = *(const float4*)(Bt + (size_t)(bn + lr) * Dq + k0 + lc);
        __syncthreads();
        As[lc + 0][lr] = va.x; As[lc + 1][lr] = va.y; As[lc + 2][lr] = va.z; As[lc + 3][lr] = va.w;
        Bs[lc + 0][lr] = vb.x; Bs[lc + 1][lr] = vb.y; Bs[lc + 2][lr] = vb.z; Bs[lc + 3][lr] = vb.w;
        __syncthreads();
#pragma unroll
        for (int kk = 0; kk < 8; ++kk) {
            float ra[8], rb[8];
#pragma unroll
            for (int ib = 0; ib < 2; ++ib)
#pragma unroll
                for (int ii = 0; ii < 4; ++ii) ra[ib * 4 + ii] = As[kk][ty * 4 + ii + 64 * ib];
#pragma unroll
            for (int jb = 0; jb < 2; ++jb)
#pragma unroll
                for (int jj = 0; jj < 4; ++jj) rb[jb * 4 + jj] = Bs[kk][tx * 4 + jj + 64 * jb];
#pragma unroll
            for (int i = 0; i < 8; ++i)
#pragma unroll
                for (int j = 0; j < 8; ++j) acc[i][j] += ra[i] * rb[j];
        }
    }
#pragma unroll
    for (int ib = 0; ib < 2; ++ib)
#pragma unroll
        for (int ii = 0; ii < 4; ++ii) {
            int row = bm + ty * 4 + ii + 64 * ib;
#pragma unroll
            for (int jb = 0; jb < 2; ++jb) {
                int col0 = bn + tx * 4 + 64 * jb;
                float4 v;
                v.x = acc[ib * 4 + ii][jb * 4 + 0];
                v.y = acc[ib * 4 + ii][jb * 4 + 1];
                v.z = acc[ib * 4 + ii][jb * 4 + 2];
                v.w = acc[ib * 4 + ii][jb * 4 + 3];
                if (withBias) {
                    v.x += bias[col0 + 0]; v.y += bias[col0 + 1];
                    v.z += bias[col0 + 2]; v.w += bias[col0 + 3];
                }
                *(float4*)(Cc + (size_t)row * Nn + col0) = v;
            }
        }
}

__global__ __launch_bounds__(256) void gemm_fw_kernel(const float* __restrict__ W,
                                                      const float* __restrict__ bias) {
    gemm_body(g_pooled, W, bias, g_f, Dq, 1);
}
__global__ __launch_bounds__(256) void gemm_sim_kernel() {
    gemm_body(g_f, g_f, nullptr, g_sim, Nq, 0);
}

// ---------- row-normalize f in place, one wave per row ----------
__global__ __launch_bounds__(256) void normalize_kernel() {
    int row  = (int)((blockIdx.x * blockDim.x + threadIdx.x) >> 6);
    int lane = threadIdx.x & 63;
    if (row >= Nq) return;
    float ss = 0.f;
    float v[Dq / 64];
#pragma unroll
    for (int j = 0; j < Dq / 64; ++j) { v[j] = g_f[(size_t)row * Dq + j * 64 + lane]; ss += v[j] * v[j]; }
#pragma unroll
    for (int o = 32; o > 0; o >>= 1) ss += __shfl_xor(ss, o, 64);
    float rn = 1.f / sqrtf(ss);
#pragma unroll
    for (int j = 0; j < Dq / 64; ++j) g_f[(size_t)row * Dq + j * 64 + lane] = v[j] * rn;
}

// ---------- per-row safe count, safe max, pos ----------
__global__ __launch_bounds__(256) void count_kernel() {
    int i = blockIdx.x;
    const float* row = g_sim + (size_t)i * Nq;
    int labi = i & 2047;
    int cnt = 0; float mx = -1e30f;
    for (int j = threadIdx.x; j < Nq; j += 256) {
        float v = row[j];
        if (v <= 0.9f && ((j & 2047) != labi)) { cnt++; mx = fmaxf(mx, v); }
    }
    __shared__ int sc[256]; __shared__ float sm[256];
    sc[threadIdx.x] = cnt; sm[threadIdx.x] = mx; __syncthreads();
    for (int o = 128; o > 0; o >>= 1) {
        if (threadIdx.x < o) {
            sc[threadIdx.x] += sc[threadIdx.x + o];
            sm[threadIdx.x] = fmaxf(sm[threadIdx.x], sm[threadIdx.x + o]);
        }
        __syncthreads();
    }
    if (threadIdx.x == 0) {
        g_counts[i] = sc[0];
        g_rowmax[i] = sm[0];
        g_pos[i]    = row[(i + Bq) & (Nq - 1)];
    }
}

// ---------- global k ----------
__global__ __launch_bounds__(256) void k_kernel() {
    int s = 0;
    for (int i = threadIdx.x; i < Nq; i += 256) s += g_counts[i];
    __shared__ int sc[256];
    sc[threadIdx.x] = s; __syncthreads();
    for (int o = 128; o > 0; o >>= 1) {
        if (threadIdx.x < o) sc[threadIdx.x] += sc[threadIdx.x + o];
        __syncthreads();
    }
    if (threadIdx.x == 0) { int k = sc[0] / (2 * Nq); g_kk = k < 1 ? 1 : k; }
}

// ---------- per-row top-k logsumexp via histogram selection ----------
__global__ __launch_bounds__(256) void lse_kernel() {
    int i = blockIdx.x;
    const float* row = g_sim + (size_t)i * Nq;
    int labi = i & 2047;
    int k   = g_kk;
    int cnt = g_counts[i];
    float pos = g_pos[i];
    float mxs = (cnt > 0) ? g_rowmax[i] : -10.0f;
    float ml  = fmaxf(pos, mxs) / TEMPq;

    __shared__ unsigned int hist[NBIN];
    for (int b = threadIdx.x; b < NBIN; b += 256) hist[b] = 0u;
    __syncthreads();
    for (int j = threadIdx.x; j < Nq; j += 256) {
        float v = row[j];
        if (v <= 0.9f && ((j & 2047) != labi)) {
            int b = (int)((v + 1.0f) * 2048.0f);
            b = b < 0 ? 0 : (b > NBIN - 1 ? NBIN - 1 : b);
            atomicAdd(&hist[b], 1u);
        }
    }
    __syncthreads();
    __shared__ unsigned int part[256];
    {
        unsigned int ps = 0;
        int b0 = threadIdx.x * 16;
        for (int b = b0; b < b0 + 16; ++b) ps += hist[b];
        part[threadIdx.x] = ps;
    }
    __syncthreads();
    __shared__ int s_bin, s_chi;
    if (threadIdx.x == 0) {
        if (cnt <= k) { s_bin = -1; s_chi = 0; }
        else {
            int acc = 0; int pb = 255;
            for (; pb >= 0; --pb) { int p = (int)part[pb]; if (acc + p >= k) break; acc += p; }
            if (pb < 0) { s_bin = -1; s_chi = 0; }
            else {
                int b = pb * 16 + 15;
                for (; b > pb * 16; --b) { int h = (int)hist[b]; if (acc + h >= k) break; acc += h; }
                s_bin = b; s_chi = acc;
            }
        }
    }
    __syncthreads();
    int bin_t = s_bin, chi = s_chi;
    float shi = 0.f, st = 0.f;
    for (int j = threadIdx.x; j < Nq; j += 256) {
        float v = row[j];
        if (v <= 0.9f && ((j & 2047) != labi)) {
            int b = (int)((v + 1.0f) * 2048.0f);
            b = b < 0 ? 0 : (b > NBIN - 1 ? NBIN - 1 : b);
            float ev = expf(v / TEMPq - ml);
            if (b > bin_t) shi += ev;
            else if (b == bin_t) st += ev;
        }
    }
    __shared__ float r1[256], r2[256];
    r1[threadIdx.x] = shi; r2[threadIdx.x] = st; __syncthreads();
    for (int o = 128; o > 0; o >>= 1) {
        if (threadIdx.x < o) { r1[threadIdx.x] += r1[threadIdx.x + o]; r2[threadIdx.x] += r2[threadIdx.x + o]; }
        __syncthreads();
    }
    if (threadIdx.x == 0) {
        float S = expf(pos / TEMPq - ml) + r1[0];
        if (bin_t >= 0) {
            float ntc  = (float)hist[bin_t];
            float need = (float)(k - chi);
            S += r2[0] * (need / ntc);
        }
        g_rowloss[i] = (logf(S) + ml) - pos / TEMPq;
    }
}

// ---------- final mean ----------
__global__ __launch_bounds__(256) void loss_kernel(float* __restrict__ out) {
    float s = 0.f;
    for (int i = threadIdx.x; i < Nq; i += 256) s += g_rowloss[i];
    __shared__ float sm[256];
    sm[threadIdx.x] = s; __syncthreads();
    for (int o = 128; o > 0; o >>= 1) {
        if (threadIdx.x < o) sm[threadIdx.x] += sm[threadIdx.x + o];
        __syncthreads();
    }
    if (threadIdx.x == 0) out[0] = sm[0] / (float)Nq;
}

extern "C" void kernel_launch(void* const* d_in, const int* in_sizes, int n_in,
                              void* d_out, int out_size, void* d_ws, size_t ws_size,
                              hipStream_t stream) {
    const float* z         = (const float*)d_in[0];
    const float* query     = (const float*)d_in[3];
    const float* attn_temp = (const float*)d_in[4];
    const float* W         = (const float*)d_in[5];
    const float* bias      = (const float*)d_in[6];
    float* out = (float*)d_out;

    scores_kernel<<<NTOT / 4, 256, 0, stream>>>(z, query, attn_temp);
    max_kernel<<<2, 256, 0, stream>>>();
    pool_kernel<<<Nq / 4, 256, 0, stream>>>(z);
    gemm_fw_kernel<<<dim3(Dq / 128, Nq / 128), 256, 0, stream>>>(W, bias);
    normalize_kernel<<<Nq / 4, 256, 0, stream>>>();
    gemm_sim_kernel<<<dim3(Nq / 128, Nq / 128), 256, 0, stream>>>();
    count_kernel<<<Nq, 256, 0, stream>>>();
    k_kernel<<<1, 256, 0, stream>>>();
    lse_kernel<<<Nq, 256, 0, stream>>>();
    loss_kernel<<<1, 256, 0, stream>>>(out);
}

// Round 2
// 279.451 us; speedup vs baseline: 1.9294x; 1.9294x over previous
//
#include <hip/hip_runtime.h>
#include <hip/hip_bf16.h>
#include <math.h>

#define Bq   2048
#define Cq   8
#define Dq   768
#define NROW 16384      // B*C per half
#define NTOT 32768      // 2*B*C
#define Nq   4096       // 2*B rows of f
#define TEMPq 0.07f
#define NBIN 4096

typedef __attribute__((ext_vector_type(8))) short bf16x8;
typedef __attribute__((ext_vector_type(4))) float f32x4;

// persistent device scratch (fully overwritten every call -> deterministic)
__device__ float          g_pooled[(size_t)Nq * Dq];
__device__ float          g_f[(size_t)Nq * Dq];
__device__ __hip_bfloat16 g_fb[(size_t)Nq * Dq];
__device__ float          g_sim[(size_t)Nq * Nq];
__device__ int            g_counts[Nq];
__device__ float          g_rowmax[Nq];
__device__ float          g_pos[Nq];
__device__ int            g_kk;
__device__ float          g_rowloss[Nq];

#define GLDS16(src, dst) __builtin_amdgcn_global_load_lds( \
    (const __attribute__((address_space(1))) void*)(src),  \
    (__attribute__((address_space(3))) void*)(dst), 16, 0, 0)

// ---------- fused scores + segment softmax + pooling: one wave per segment ----------
// softmax is shift-invariant, so the segment-local max replaces the global max
// exactly (the 1e-8 denom epsilon changes by <=2x on a denom of ~8 -> 1e-9 rel).
__global__ __launch_bounds__(256) void pool_fused_kernel(const float* __restrict__ z,
                                                         const float* __restrict__ query,
                                                         const float* __restrict__ attn_temp) {
    int seg  = (int)((blockIdx.x * blockDim.x + threadIdx.x) >> 6);
    int lane = threadIdx.x & 63;
    if (seg >= Nq) return;
    int half = seg >> 11;
    int b    = seg & 2047;
    int baseRow = half * NROW + b * Cq;
    float invt = 1.f / attn_temp[0];

    float q[Dq / 64];
#pragma unroll
    for (int j = 0; j < Dq / 64; ++j) q[j] = query[j * 64 + lane];

    float v[Cq][Dq / 64];
    float s[Cq];
#pragma unroll
    for (int c = 0; c < Cq; ++c) {
        const float* zr = z + (size_t)(baseRow + c) * Dq;
        float acc = 0.f;
#pragma unroll
        for (int j = 0; j < Dq / 64; ++j) { v[c][j] = zr[j * 64 + lane]; acc += v[c][j] * q[j]; }
#pragma unroll
        for (int o = 32; o > 0; o >>= 1) acc += __shfl_xor(acc, o, 64);
        s[c] = acc * invt;
    }
    float m = s[0];
#pragma unroll
    for (int c = 1; c < Cq; ++c) m = fmaxf(m, s[c]);
    float e[Cq], denom = 0.f;
#pragma unroll
    for (int c = 0; c < Cq; ++c) { e[c] = expf(s[c] - m); denom += e[c]; }
    float inv = 1.f / (denom + 1e-8f);
#pragma unroll
    for (int j = 0; j < Dq / 64; ++j) {
        float acc = 0.f;
#pragma unroll
        for (int c = 0; c < Cq; ++c) acc += v[c][j] * e[c];
        g_pooled[(size_t)seg * Dq + j * 64 + lane] = acc * inv;
    }
}

// ---------- fp32 GEMM for f = pooled @ W.T + b (4.8 GFLOP, keep fp32 for accuracy) ----------
__global__ __launch_bounds__(256) void gemm_fw_kernel(const float* __restrict__ W,
                                                      const float* __restrict__ bias) {
    const float* A  = g_pooled;
    const float* Bt = W;
    float* Cc = g_f;
    __shared__ float As[8][128];
    __shared__ float Bs[8][128];
    const int tid = threadIdx.x;
    const int tx = tid & 15;
    const int ty = tid >> 4;
    const int bm = blockIdx.y * 128;
    const int bn = blockIdx.x * 128;
    float acc[8][8];
#pragma unroll
    for (int i = 0; i < 8; ++i)
#pragma unroll
        for (int j = 0; j < 8; ++j) acc[i][j] = 0.f;

    const int lr = tid >> 1;
    const int lc = (tid & 1) * 4;

    for (int k0 = 0; k0 < Dq; k0 += 8) {
        float4 va = *(const float4*)(A  + (size_t)(bm + lr) * Dq + k0 + lc);
        float4 vb = *(const float4*)(Bt + (size_t)(bn + lr) * Dq + k0 + lc);
        __syncthreads();
        As[lc + 0][lr] = va.x; As[lc + 1][lr] = va.y; As[lc + 2][lr] = va.z; As[lc + 3][lr] = va.w;
        Bs[lc + 0][lr] = vb.x; Bs[lc + 1][lr] = vb.y; Bs[lc + 2][lr] = vb.z; Bs[lc + 3][lr] = vb.w;
        __syncthreads();
#pragma unroll
        for (int kk = 0; kk < 8; ++kk) {
            float ra[8], rb[8];
#pragma unroll
            for (int ib = 0; ib < 2; ++ib)
#pragma unroll
                for (int ii = 0; ii < 4; ++ii) ra[ib * 4 + ii] = As[kk][ty * 4 + ii + 64 * ib];
#pragma unroll
            for (int jb = 0; jb < 2; ++jb)
#pragma unroll
                for (int jj = 0; jj < 4; ++jj) rb[jb * 4 + jj] = Bs[kk][tx * 4 + jj + 64 * jb];
#pragma unroll
            for (int i = 0; i < 8; ++i)
#pragma unroll
                for (int j = 0; j < 8; ++j) acc[i][j] += ra[i] * rb[j];
        }
    }
#pragma unroll
    for (int ib = 0; ib < 2; ++ib)
#pragma unroll
        for (int ii = 0; ii < 4; ++ii) {
            int row = bm + ty * 4 + ii + 64 * ib;
#pragma unroll
            for (int jb = 0; jb < 2; ++jb) {
                int col0 = bn + tx * 4 + 64 * jb;
                float4 vv;
                vv.x = acc[ib * 4 + ii][jb * 4 + 0] + bias[col0 + 0];
                vv.y = acc[ib * 4 + ii][jb * 4 + 1] + bias[col0 + 1];
                vv.z = acc[ib * 4 + ii][jb * 4 + 2] + bias[col0 + 2];
                vv.w = acc[ib * 4 + ii][jb * 4 + 3] + bias[col0 + 3];
                *(float4*)(Cc + (size_t)row * Dq + col0) = vv;
            }
        }
}

// ---------- row-normalize -> bf16, one wave per row ----------
__global__ __launch_bounds__(256) void normalize_kernel() {
    int row  = (int)((blockIdx.x * blockDim.x + threadIdx.x) >> 6);
    int lane = threadIdx.x & 63;
    if (row >= Nq) return;
    float ss = 0.f;
    float v[Dq / 64];
#pragma unroll
    for (int j = 0; j < Dq / 64; ++j) { v[j] = g_f[(size_t)row * Dq + j * 64 + lane]; ss += v[j] * v[j]; }
#pragma unroll
    for (int o = 32; o > 0; o >>= 1) ss += __shfl_xor(ss, o, 64);
    float rn = 1.f / sqrtf(ss);
#pragma unroll
    for (int j = 0; j < Dq / 64; ++j)
        g_fb[(size_t)row * Dq + j * 64 + lane] = __float2bfloat16(v[j] * rn);
}

// ---------- sim = fb @ fb^T via bf16 MFMA, upper-triangular blocks + mirror store ----------
__global__ __launch_bounds__(256) void sim_mfma_kernel() {
    __shared__ short lA[128 * 32];
    __shared__ short lB[128 * 32];

    // map linear block id -> upper-triangular (bi, bj), bi <= bj, 32x32 block grid
    int t = blockIdx.x;
    int bi = 0, rem = t;
    while (rem >= (32 - bi)) { rem -= (32 - bi); ++bi; }
    int bj = bi + rem;
    int bm = bi * 128, bn = bj * 128;

    const int tid  = threadIdx.x;
    const int wave = tid >> 6, lane = tid & 63;
    const int wr = wave >> 1, wc = wave & 1;

    const short* fb = (const short*)g_fb;

    // staging: chunk c covers rows c*16..c*16+15 of the 128x32 tile (1024 B);
    // lane l -> row c*16 + (l>>2), elem col (l&3)*8  (matches linear LDS dest)
    const int c0 = wave * 2, c1 = wave * 2 + 1;
    const int srow = lane >> 2;
    const int scol = (lane & 3) * 8;

    f32x4 acc[4][4];
#pragma unroll
    for (int m = 0; m < 4; ++m)
#pragma unroll
        for (int n = 0; n < 4; ++n) acc[m][n] = (f32x4){0.f, 0.f, 0.f, 0.f};

    for (int k0 = 0; k0 < Dq; k0 += 32) {
        GLDS16(fb + (size_t)(bm + c0 * 16 + srow) * Dq + k0 + scol, lA + c0 * 512);
        GLDS16(fb + (size_t)(bm + c1 * 16 + srow) * Dq + k0 + scol, lA + c1 * 512);
        GLDS16(fb + (size_t)(bn + c0 * 16 + srow) * Dq + k0 + scol, lB + c0 * 512);
        GLDS16(fb + (size_t)(bn + c1 * 16 + srow) * Dq + k0 + scol, lB + c1 * 512);
        __syncthreads();   // compiler drains vmcnt before barrier

        bf16x8 af[4], bfr[4];
#pragma unroll
        for (int m = 0; m < 4; ++m) {
            int row = wr * 64 + m * 16 + (lane & 15);
            af[m] = *(const bf16x8*)(lA + row * 32 + (lane >> 4) * 8);
        }
#pragma unroll
        for (int n = 0; n < 4; ++n) {
            int row = wc * 64 + n * 16 + (lane & 15);
            bfr[n] = *(const bf16x8*)(lB + row * 32 + (lane >> 4) * 8);
        }
#pragma unroll
        for (int m = 0; m < 4; ++m)
#pragma unroll
            for (int n = 0; n < 4; ++n)
                acc[m][n] = __builtin_amdgcn_mfma_f32_16x16x32_bf16(af[m], bfr[n], acc[m][n], 0, 0, 0);
        __syncthreads();   // protect LDS before next overwrite
    }

    // C/D frag layout: col = lane&15, row = (lane>>4)*4 + reg  [m89]
#pragma unroll
    for (int m = 0; m < 4; ++m) {
        int rowb = bm + wr * 64 + m * 16 + (lane >> 4) * 4;
#pragma unroll
        for (int n = 0; n < 4; ++n) {
            int col = bn + wc * 64 + n * 16 + (lane & 15);
#pragma unroll
            for (int j = 0; j < 4; ++j)
                g_sim[(size_t)(rowb + j) * Nq + col] = acc[m][n][j];
        }
    }
    if (bi != bj) {
        // mirror store: transposed, the 4 acc regs are 4 consecutive rows -> float4
#pragma unroll
        for (int m = 0; m < 4; ++m) {
            int rowb = bm + wr * 64 + m * 16 + (lane >> 4) * 4;
#pragma unroll
            for (int n = 0; n < 4; ++n) {
                int col = bn + wc * 64 + n * 16 + (lane & 15);
                *(f32x4*)&g_sim[(size_t)col * Nq + rowb] = acc[m][n];
            }
        }
    }
}

// ---------- per-row safe count, safe max, pos ----------
__global__ __launch_bounds__(256) void count_kernel() {
    int i = blockIdx.x;
    const float* row = g_sim + (size_t)i * Nq;
    int labi = i & 2047;
    int cnt = 0; float mx = -1e30f;
    for (int j = threadIdx.x; j < Nq; j += 256) {
        float v = row[j];
        if (v <= 0.9f && ((j & 2047) != labi)) { cnt++; mx = fmaxf(mx, v); }
    }
    __shared__ int sc[256]; __shared__ float sm[256];
    sc[threadIdx.x] = cnt; sm[threadIdx.x] = mx; __syncthreads();
    for (int o = 128; o > 0; o >>= 1) {
        if (threadIdx.x < o) {
            sc[threadIdx.x] += sc[threadIdx.x + o];
            sm[threadIdx.x] = fmaxf(sm[threadIdx.x], sm[threadIdx.x + o]);
        }
        __syncthreads();
    }
    if (threadIdx.x == 0) {
        g_counts[i] = sc[0];
        g_rowmax[i] = sm[0];
        g_pos[i]    = row[(i + Bq) & (Nq - 1)];
    }
}

// ---------- global k ----------
__global__ __launch_bounds__(256) void k_kernel() {
    int s = 0;
    for (int i = threadIdx.x; i < Nq; i += 256) s += g_counts[i];
    __shared__ int sc[256];
    sc[threadIdx.x] = s; __syncthreads();
    for (int o = 128; o > 0; o >>= 1) {
        if (threadIdx.x < o) sc[threadIdx.x] += sc[threadIdx.x + o];
        __syncthreads();
    }
    if (threadIdx.x == 0) { int k = sc[0] / (2 * Nq); g_kk = k < 1 ? 1 : k; }
}

// ---------- per-row top-k logsumexp via histogram selection (row staged in LDS) ----------
__global__ __launch_bounds__(256) void lse_kernel() {
    int i = blockIdx.x;
    const float* row = g_sim + (size_t)i * Nq;
    int labi = i & 2047;
    int k   = g_kk;
    int cnt = g_counts[i];
    float pos = g_pos[i];
    float mxs = (cnt > 0) ? g_rowmax[i] : -10.0f;
    float ml  = fmaxf(pos, mxs) / TEMPq;

    __shared__ float srow[Nq];
    __shared__ unsigned int hist[NBIN];
    for (int b = threadIdx.x; b < NBIN; b += 256) hist[b] = 0u;
    __syncthreads();
    for (int j = threadIdx.x; j < Nq; j += 256) {
        float v = row[j];
        srow[j] = v;
        if (v <= 0.9f && ((j & 2047) != labi)) {
            int b = (int)((v + 1.0f) * 2048.0f);
            b = b < 0 ? 0 : (b > NBIN - 1 ? NBIN - 1 : b);
            atomicAdd(&hist[b], 1u);
        }
    }
    __syncthreads();
    __shared__ unsigned int part[256];
    {
        unsigned int ps = 0;
        int b0 = threadIdx.x * 16;
        for (int b = b0; b < b0 + 16; ++b) ps += hist[b];
        part[threadIdx.x] = ps;
    }
    __syncthreads();
    __shared__ int s_bin, s_chi;
    if (threadIdx.x == 0) {
        if (cnt <= k) { s_bin = -1; s_chi = 0; }
        else {
            int acc = 0; int pb = 255;
            for (; pb >= 0; --pb) { int p = (int)part[pb]; if (acc + p >= k) break; acc += p; }
            if (pb < 0) { s_bin = -1; s_chi = 0; }
            else {
                int b = pb * 16 + 15;
                for (; b > pb * 16; --b) { int h = (int)hist[b]; if (acc + h >= k) break; acc += h; }
                s_bin = b; s_chi = acc;
            }
        }
    }
    __syncthreads();
    int bin_t = s_bin, chi = s_chi;
    float shi = 0.f, st = 0.f;
    for (int j = threadIdx.x; j < Nq; j += 256) {
        float v = srow[j];
        if (v <= 0.9f && ((j & 2047) != labi)) {
            int b = (int)((v + 1.0f) * 2048.0f);
            b = b < 0 ? 0 : (b > NBIN - 1 ? NBIN - 1 : b);
            float ev = expf(v / TEMPq - ml);
            if (b > bin_t) shi += ev;
            else if (b == bin_t) st += ev;
        }
    }
    __shared__ float r1[256], r2[256];
    r1[threadIdx.x] = shi; r2[threadIdx.x] = st; __syncthreads();
    for (int o = 128; o > 0; o >>= 1) {
        if (threadIdx.x < o) { r1[threadIdx.x] += r1[threadIdx.x + o]; r2[threadIdx.x] += r2[threadIdx.x + o]; }
        __syncthreads();
    }
    if (threadIdx.x == 0) {
        float S = expf(pos / TEMPq - ml) + r1[0];
        if (bin_t >= 0) {
            float ntc  = (float)hist[bin_t];
            float need = (float)(k - chi);
            S += r2[0] * (need / ntc);
        }
        g_rowloss[i] = (logf(S) + ml) - pos / TEMPq;
    }
}

// ---------- final mean ----------
__global__ __launch_bounds__(256) void loss_kernel(float* __restrict__ out) {
    float s = 0.f;
    for (int i = threadIdx.x; i < Nq; i += 256) s += g_rowloss[i];
    __shared__ float sm[256];
    sm[threadIdx.x] = s; __syncthreads();
    for (int o = 128; o > 0; o >>= 1) {
        if (threadIdx.x < o) sm[threadIdx.x] += sm[threadIdx.x + o];
        __syncthreads();
    }
    if (threadIdx.x == 0) out[0] = sm[0] / (float)Nq;
}

extern "C" void kernel_launch(void* const* d_in, const int* in_sizes, int n_in,
                              void* d_out, int out_size, void* d_ws, size_t ws_size,
                              hipStream_t stream) {
    const float* z         = (const float*)d_in[0];
    const float* query     = (const float*)d_in[3];
    const float* attn_temp = (const float*)d_in[4];
    const float* W         = (const float*)d_in[5];
    const float* bias      = (const float*)d_in[6];
    float* out = (float*)d_out;

    pool_fused_kernel<<<Nq / 4, 256, 0, stream>>>(z, query, attn_temp);
    gemm_fw_kernel<<<dim3(Dq / 128, Nq / 128), 256, 0, stream>>>(W, bias);
    normalize_kernel<<<Nq / 4, 256, 0, stream>>>();
    sim_mfma_kernel<<<(32 * 33) / 2, 256, 0, stream>>>();
    count_kernel<<<Nq, 256, 0, stream>>>();
    k_kernel<<<1, 256, 0, stream>>>();
    lse_kernel<<<Nq, 256, 0, stream>>>();
    loss_kernel<<<1, 256, 0, stream>>>(out);
}

// Round 3
// 193.602 us; speedup vs baseline: 2.7850x; 1.4434x over previous
//
#include <hip/hip_runtime.h>
#include <hip/hip_bf16.h>
#include <math.h>

#define Bq   2048
#define Cq   8
#define Dq   768
#define NROW 16384      // B*C per half
#define NTOT 32768      // 2*B*C
#define Nq   4096       // 2*B rows of f
#define TEMPq 0.07f
#define NBIN 4096

typedef __attribute__((ext_vector_type(8))) short bf16x8;
typedef __attribute__((ext_vector_type(4))) float f32x4;

// persistent device scratch (fully overwritten every call -> deterministic)
__device__ __hip_bfloat16 g_pooledb[(size_t)Nq * Dq];
__device__ __hip_bfloat16 g_Wb[(size_t)Dq * Dq];
__device__ float          g_f[(size_t)Nq * Dq];
__device__ __hip_bfloat16 g_fb[(size_t)Nq * Dq];
__device__ float          g_sim[(size_t)Nq * Nq];
__device__ int            g_counts[Nq];
__device__ float          g_rowmax[Nq];
__device__ float          g_pos[Nq];
__device__ int            g_kk;
__device__ float          g_rowloss[Nq];

#define GLDS16(src, dst) __builtin_amdgcn_global_load_lds( \
    (const __attribute__((address_space(1))) void*)(src),  \
    (__attribute__((address_space(3))) void*)(dst), 16, 0, 0)

// ---------- fused scores + segment softmax + pooling: one wave per segment ----------
__global__ __launch_bounds__(256) void pool_fused_kernel(const float* __restrict__ z,
                                                         const float* __restrict__ query,
                                                         const float* __restrict__ attn_temp) {
    int seg  = (int)((blockIdx.x * blockDim.x + threadIdx.x) >> 6);
    int lane = threadIdx.x & 63;
    if (seg >= Nq) return;
    int half = seg >> 11;
    int b    = seg & 2047;
    int baseRow = half * NROW + b * Cq;
    float invt = 1.f / attn_temp[0];

    float q[Dq / 64];
#pragma unroll
    for (int j = 0; j < Dq / 64; ++j) q[j] = query[j * 64 + lane];

    float v[Cq][Dq / 64];
    float s[Cq];
#pragma unroll
    for (int c = 0; c < Cq; ++c) {
        const float* zr = z + (size_t)(baseRow + c) * Dq;
        float acc = 0.f;
#pragma unroll
        for (int j = 0; j < Dq / 64; ++j) { v[c][j] = zr[j * 64 + lane]; acc += v[c][j] * q[j]; }
#pragma unroll
        for (int o = 32; o > 0; o >>= 1) acc += __shfl_xor(acc, o, 64);
        s[c] = acc * invt;
    }
    float m = s[0];
#pragma unroll
    for (int c = 1; c < Cq; ++c) m = fmaxf(m, s[c]);
    float e[Cq], denom = 0.f;
#pragma unroll
    for (int c = 0; c < Cq; ++c) { e[c] = expf(s[c] - m); denom += e[c]; }
    float inv = 1.f / (denom + 1e-8f);
#pragma unroll
    for (int j = 0; j < Dq / 64; ++j) {
        float acc = 0.f;
#pragma unroll
        for (int c = 0; c < Cq; ++c) acc += v[c][j] * e[c];
        g_pooledb[(size_t)seg * Dq + j * 64 + lane] = __float2bfloat16(acc * inv);
    }
}

// ---------- W -> bf16 (589824 elems, 4 per thread) ----------
__global__ __launch_bounds__(256) void wconv_kernel(const float* __restrict__ W) {
    int i = blockIdx.x * 256 + threadIdx.x;   // float4 group index
    float4 v = ((const float4*)W)[i];
    short4 o;
    o.x = ((__hip_bfloat16_raw)__float2bfloat16(v.x)).x;
    o.y = ((__hip_bfloat16_raw)__float2bfloat16(v.y)).x;
    o.z = ((__hip_bfloat16_raw)__float2bfloat16(v.z)).x;
    o.w = ((__hip_bfloat16_raw)__float2bfloat16(v.w)).x;
    ((short4*)g_Wb)[i] = o;
}

// ---------- f = pooled @ W^T + b via bf16 MFMA (M=4096, N=768, K=768) ----------
__global__ __launch_bounds__(256) void fw_mfma_kernel(const float* __restrict__ bias) {
    __shared__ short lA[128 * 32];
    __shared__ short lB[128 * 32];
    const int bm = blockIdx.y * 128;
    const int bn = blockIdx.x * 128;

    const int tid  = threadIdx.x;
    const int wave = tid >> 6, lane = tid & 63;
    const int wr = wave >> 1, wc = wave & 1;

    const short* A = (const short*)g_pooledb;
    const short* Bt = (const short*)g_Wb;

    const int c0 = wave * 2, c1 = wave * 2 + 1;
    const int srow = lane >> 2;
    const int scol = (lane & 3) * 8;

    f32x4 acc[4][4];
#pragma unroll
    for (int m = 0; m < 4; ++m)
#pragma unroll
        for (int n = 0; n < 4; ++n) acc[m][n] = (f32x4){0.f, 0.f, 0.f, 0.f};

    for (int k0 = 0; k0 < Dq; k0 += 32) {
        GLDS16(A  + (size_t)(bm + c0 * 16 + srow) * Dq + k0 + scol, lA + c0 * 512);
        GLDS16(A  + (size_t)(bm + c1 * 16 + srow) * Dq + k0 + scol, lA + c1 * 512);
        GLDS16(Bt + (size_t)(bn + c0 * 16 + srow) * Dq + k0 + scol, lB + c0 * 512);
        GLDS16(Bt + (size_t)(bn + c1 * 16 + srow) * Dq + k0 + scol, lB + c1 * 512);
        __syncthreads();

        bf16x8 af[4], bfr[4];
#pragma unroll
        for (int m = 0; m < 4; ++m) {
            int row = wr * 64 + m * 16 + (lane & 15);
            af[m] = *(const bf16x8*)(lA + row * 32 + (lane >> 4) * 8);
        }
#pragma unroll
        for (int n = 0; n < 4; ++n) {
            int row = wc * 64 + n * 16 + (lane & 15);
            bfr[n] = *(const bf16x8*)(lB + row * 32 + (lane >> 4) * 8);
        }
#pragma unroll
        for (int m = 0; m < 4; ++m)
#pragma unroll
            for (int n = 0; n < 4; ++n)
                acc[m][n] = __builtin_amdgcn_mfma_f32_16x16x32_bf16(af[m], bfr[n], acc[m][n], 0, 0, 0);
        __syncthreads();
    }

#pragma unroll
    for (int m = 0; m < 4; ++m) {
        int rowb = bm + wr * 64 + m * 16 + (lane >> 4) * 4;
#pragma unroll
        for (int n = 0; n < 4; ++n) {
            int col = bn + wc * 64 + n * 16 + (lane & 15);
            float bc = bias[col];
#pragma unroll
            for (int j = 0; j < 4; ++j)
                g_f[(size_t)(rowb + j) * Dq + col] = acc[m][n][j] + bc;
        }
    }
}

// ---------- row-normalize -> bf16, one wave per row ----------
__global__ __launch_bounds__(256) void normalize_kernel() {
    int row  = (int)((blockIdx.x * blockDim.x + threadIdx.x) >> 6);
    int lane = threadIdx.x & 63;
    if (row >= Nq) return;
    float ss = 0.f;
    float v[Dq / 64];
#pragma unroll
    for (int j = 0; j < Dq / 64; ++j) { v[j] = g_f[(size_t)row * Dq + j * 64 + lane]; ss += v[j] * v[j]; }
#pragma unroll
    for (int o = 32; o > 0; o >>= 1) ss += __shfl_xor(ss, o, 64);
    float rn = 1.f / sqrtf(ss);
#pragma unroll
    for (int j = 0; j < Dq / 64; ++j)
        g_fb[(size_t)row * Dq + j * 64 + lane] = __float2bfloat16(v[j] * rn);
}

// ---------- sim = fb @ fb^T via bf16 MFMA, upper-triangular blocks + mirror store ----------
__global__ __launch_bounds__(256) void sim_mfma_kernel() {
    __shared__ short lA[128 * 32];
    __shared__ short lB[128 * 32];

    int t = blockIdx.x;
    int bi = 0, rem = t;
    while (rem >= (32 - bi)) { rem -= (32 - bi); ++bi; }
    int bj = bi + rem;
    int bm = bi * 128, bn = bj * 128;

    const int tid  = threadIdx.x;
    const int wave = tid >> 6, lane = tid & 63;
    const int wr = wave >> 1, wc = wave & 1;

    const short* fb = (const short*)g_fb;

    const int c0 = wave * 2, c1 = wave * 2 + 1;
    const int srow = lane >> 2;
    const int scol = (lane & 3) * 8;

    f32x4 acc[4][4];
#pragma unroll
    for (int m = 0; m < 4; ++m)
#pragma unroll
        for (int n = 0; n < 4; ++n) acc[m][n] = (f32x4){0.f, 0.f, 0.f, 0.f};

    for (int k0 = 0; k0 < Dq; k0 += 32) {
        GLDS16(fb + (size_t)(bm + c0 * 16 + srow) * Dq + k0 + scol, lA + c0 * 512);
        GLDS16(fb + (size_t)(bm + c1 * 16 + srow) * Dq + k0 + scol, lA + c1 * 512);
        GLDS16(fb + (size_t)(bn + c0 * 16 + srow) * Dq + k0 + scol, lB + c0 * 512);
        GLDS16(fb + (size_t)(bn + c1 * 16 + srow) * Dq + k0 + scol, lB + c1 * 512);
        __syncthreads();

        bf16x8 af[4], bfr[4];
#pragma unroll
        for (int m = 0; m < 4; ++m) {
            int row = wr * 64 + m * 16 + (lane & 15);
            af[m] = *(const bf16x8*)(lA + row * 32 + (lane >> 4) * 8);
        }
#pragma unroll
        for (int n = 0; n < 4; ++n) {
            int row = wc * 64 + n * 16 + (lane & 15);
            bfr[n] = *(const bf16x8*)(lB + row * 32 + (lane >> 4) * 8);
        }
#pragma unroll
        for (int m = 0; m < 4; ++m)
#pragma unroll
            for (int n = 0; n < 4; ++n)
                acc[m][n] = __builtin_amdgcn_mfma_f32_16x16x32_bf16(af[m], bfr[n], acc[m][n], 0, 0, 0);
        __syncthreads();
    }

#pragma unroll
    for (int m = 0; m < 4; ++m) {
        int rowb = bm + wr * 64 + m * 16 + (lane >> 4) * 4;
#pragma unroll
        for (int n = 0; n < 4; ++n) {
            int col = bn + wc * 64 + n * 16 + (lane & 15);
#pragma unroll
            for (int j = 0; j < 4; ++j)
                g_sim[(size_t)(rowb + j) * Nq + col] = acc[m][n][j];
        }
    }
    if (bi != bj) {
#pragma unroll
        for (int m = 0; m < 4; ++m) {
            int rowb = bm + wr * 64 + m * 16 + (lane >> 4) * 4;
#pragma unroll
            for (int n = 0; n < 4; ++n) {
                int col = bn + wc * 64 + n * 16 + (lane & 15);
                *(f32x4*)&g_sim[(size_t)col * Nq + rowb] = acc[m][n];
            }
        }
    }
}

// ---------- per-row safe count, safe max, pos ----------
__global__ __launch_bounds__(256) void count_kernel() {
    int i = blockIdx.x;
    const float* row = g_sim + (size_t)i * Nq;
    int labi = i & 2047;
    int cnt = 0; float mx = -1e30f;
    for (int j = threadIdx.x; j < Nq; j += 256) {
        float v = row[j];
        if (v <= 0.9f && ((j & 2047) != labi)) { cnt++; mx = fmaxf(mx, v); }
    }
    __shared__ int sc[256]; __shared__ float sm[256];
    sc[threadIdx.x] = cnt; sm[threadIdx.x] = mx; __syncthreads();
    for (int o = 128; o > 0; o >>= 1) {
        if (threadIdx.x < o) {
            sc[threadIdx.x] += sc[threadIdx.x + o];
            sm[threadIdx.x] = fmaxf(sm[threadIdx.x], sm[threadIdx.x + o]);
        }
        __syncthreads();
    }
    if (threadIdx.x == 0) {
        g_counts[i] = sc[0];
        g_rowmax[i] = sm[0];
        g_pos[i]    = row[(i + Bq) & (Nq - 1)];
    }
}

// ---------- global k ----------
__global__ __launch_bounds__(256) void k_kernel() {
    int s = 0;
    for (int i = threadIdx.x; i < Nq; i += 256) s += g_counts[i];
    __shared__ int sc[256];
    sc[threadIdx.x] = s; __syncthreads();
    for (int o = 128; o > 0; o >>= 1) {
        if (threadIdx.x < o) sc[threadIdx.x] += sc[threadIdx.x + o];
        __syncthreads();
    }
    if (threadIdx.x == 0) { int k = sc[0] / (2 * Nq); g_kk = k < 1 ? 1 : k; }
}

// ---------- per-row top-k logsumexp via histogram selection (row staged in LDS) ----------
__global__ __launch_bounds__(256) void lse_kernel() {
    int i = blockIdx.x;
    const float* row = g_sim + (size_t)i * Nq;
    int labi = i & 2047;
    int k   = g_kk;
    int cnt = g_counts[i];
    float pos = g_pos[i];
    float mxs = (cnt > 0) ? g_rowmax[i] : -10.0f;
    float ml  = fmaxf(pos, mxs) / TEMPq;

    __shared__ float srow[Nq];
    __shared__ unsigned int hist[NBIN];
    for (int b = threadIdx.x; b < NBIN; b += 256) hist[b] = 0u;
    __syncthreads();
    for (int j = threadIdx.x; j < Nq; j += 256) {
        float v = row[j];
        srow[j] = v;
        if (v <= 0.9f && ((j & 2047) != labi)) {
            int b = (int)((v + 1.0f) * 2048.0f);
            b = b < 0 ? 0 : (b > NBIN - 1 ? NBIN - 1 : b);
            atomicAdd(&hist[b], 1u);
        }
    }
    __syncthreads();
    __shared__ unsigned int part[256];
    {
        unsigned int ps = 0;
        int b0 = threadIdx.x * 16;
        for (int b = b0; b < b0 + 16; ++b) ps += hist[b];
        part[threadIdx.x] = ps;
    }
    __syncthreads();
    __shared__ int s_bin, s_chi;
    if (threadIdx.x == 0) {
        if (cnt <= k) { s_bin = -1; s_chi = 0; }
        else {
            int acc = 0; int pb = 255;
            for (; pb >= 0; --pb) { int p = (int)part[pb]; if (acc + p >= k) break; acc += p; }
            if (pb < 0) { s_bin = -1; s_chi = 0; }
            else {
                int b = pb * 16 + 15;
                for (; b > pb * 16; --b) { int h = (int)hist[b]; if (acc + h >= k) break; acc += h; }
                s_bin = b; s_chi = acc;
            }
        }
    }
    __syncthreads();
    int bin_t = s_bin, chi = s_chi;
    float shi = 0.f, st = 0.f;
    for (int j = threadIdx.x; j < Nq; j += 256) {
        float v = srow[j];
        if (v <= 0.9f && ((j & 2047) != labi)) {
            int b = (int)((v + 1.0f) * 2048.0f);
            b = b < 0 ? 0 : (b > NBIN - 1 ? NBIN - 1 : b);
            float ev = expf(v / TEMPq - ml);
            if (b > bin_t) shi += ev;
            else if (b == bin_t) st += ev;
        }
    }
    __shared__ float r1[256], r2[256];
    r1[threadIdx.x] = shi; r2[threadIdx.x] = st; __syncthreads();
    for (int o = 128; o > 0; o >>= 1) {
        if (threadIdx.x < o) { r1[threadIdx.x] += r1[threadIdx.x + o]; r2[threadIdx.x] += r2[threadIdx.x + o]; }
        __syncthreads();
    }
    if (threadIdx.x == 0) {
        float S = expf(pos / TEMPq - ml) + r1[0];
        if (bin_t >= 0) {
            float ntc  = (float)hist[bin_t];
            float need = (float)(k - chi);
            S += r2[0] * (need / ntc);
        }
        g_rowloss[i] = (logf(S) + ml) - pos / TEMPq;
    }
}

// ---------- final mean ----------
__global__ __launch_bounds__(256) void loss_kernel(float* __restrict__ out) {
    float s = 0.f;
    for (int i = threadIdx.x; i < Nq; i += 256) s += g_rowloss[i];
    __shared__ float sm[256];
    sm[threadIdx.x] = s; __syncthreads();
    for (int o = 128; o > 0; o >>= 1) {
        if (threadIdx.x < o) sm[threadIdx.x] += sm[threadIdx.x + o];
        __syncthreads();
    }
    if (threadIdx.x == 0) out[0] = sm[0] / (float)Nq;
}

extern "C" void kernel_launch(void* const* d_in, const int* in_sizes, int n_in,
                              void* d_out, int out_size, void* d_ws, size_t ws_size,
                              hipStream_t stream) {
    const float* z         = (const float*)d_in[0];
    const float* query     = (const float*)d_in[3];
    const float* attn_temp = (const float*)d_in[4];
    const float* W         = (const float*)d_in[5];
    const float* bias      = (const float*)d_in[6];
    float* out = (float*)d_out;

    pool_fused_kernel<<<Nq / 4, 256, 0, stream>>>(z, query, attn_temp);
    wconv_kernel<<<(Dq * Dq / 4) / 256, 256, 0, stream>>>(W);
    fw_mfma_kernel<<<dim3(Dq / 128, Nq / 128), 256, 0, stream>>>(bias);
    normalize_kernel<<<Nq / 4, 256, 0, stream>>>();
    sim_mfma_kernel<<<(32 * 33) / 2, 256, 0, stream>>>();
    count_kernel<<<Nq, 256, 0, stream>>>();
    k_kernel<<<1, 256, 0, stream>>>();
    lse_kernel<<<Nq, 256, 0, stream>>>();
    loss_kernel<<<1, 256, 0, stream>>>(out);
}

// Round 4
// 160.926 us; speedup vs baseline: 3.3504x; 1.2031x over previous
//
#include <hip/hip_runtime.h>
#include <hip/hip_bf16.h>
#include <math.h>

#define Bq   2048
#define Cq   8
#define Dq   768
#define NROW 16384      // B*C per half
#define NTOT 32768      // 2*B*C
#define Nq   4096       // 2*B rows of f
#define TEMPq 0.07f

typedef __attribute__((ext_vector_type(8))) short bf16x8;
typedef __attribute__((ext_vector_type(4))) float f32x4;

// persistent device scratch (fully overwritten every call -> deterministic)
__device__ __hip_bfloat16 g_pooledb[(size_t)Nq * Dq];
__device__ __hip_bfloat16 g_Wb[(size_t)Dq * Dq];
__device__ float          g_f[(size_t)Nq * Dq];
__device__ __hip_bfloat16 g_fb[(size_t)Nq * Dq];
__device__ float          g_sim[(size_t)Nq * Nq];
__device__ unsigned int   g_viol;
__device__ int            g_kk;
__device__ float          g_rowloss[Nq];

#define GLDS16(src, dst) __builtin_amdgcn_global_load_lds( \
    (const __attribute__((address_space(1))) void*)(src),  \
    (__attribute__((address_space(3))) void*)(dst), 16, 0, 0)

// ---------- fused scores + segment softmax + pooling: one wave per segment ----------
__global__ __launch_bounds__(256) void pool_fused_kernel(const float* __restrict__ z,
                                                         const float* __restrict__ query,
                                                         const float* __restrict__ attn_temp) {
    int seg  = (int)((blockIdx.x * blockDim.x + threadIdx.x) >> 6);
    int lane = threadIdx.x & 63;
    if (seg >= Nq) return;
    int half = seg >> 11;
    int b    = seg & 2047;
    int baseRow = half * NROW + b * Cq;
    float invt = 1.f / attn_temp[0];

    float q[Dq / 64];
#pragma unroll
    for (int j = 0; j < Dq / 64; ++j) q[j] = query[j * 64 + lane];

    float v[Cq][Dq / 64];
    float s[Cq];
#pragma unroll
    for (int c = 0; c < Cq; ++c) {
        const float* zr = z + (size_t)(baseRow + c) * Dq;
        float acc = 0.f;
#pragma unroll
        for (int j = 0; j < Dq / 64; ++j) { v[c][j] = zr[j * 64 + lane]; acc += v[c][j] * q[j]; }
#pragma unroll
        for (int o = 32; o > 0; o >>= 1) acc += __shfl_xor(acc, o, 64);
        s[c] = acc * invt;
    }
    float m = s[0];
#pragma unroll
    for (int c = 1; c < Cq; ++c) m = fmaxf(m, s[c]);
    float e[Cq], denom = 0.f;
#pragma unroll
    for (int c = 0; c < Cq; ++c) { e[c] = expf(s[c] - m); denom += e[c]; }
    float inv = 1.f / (denom + 1e-8f);
#pragma unroll
    for (int j = 0; j < Dq / 64; ++j) {
        float acc = 0.f;
#pragma unroll
        for (int c = 0; c < Cq; ++c) acc += v[c][j] * e[c];
        g_pooledb[(size_t)seg * Dq + j * 64 + lane] = __float2bfloat16(acc * inv);
    }
}

// ---------- W -> bf16, also zero the violation counter ----------
__global__ __launch_bounds__(256) void wconv_kernel(const float* __restrict__ W) {
    if (blockIdx.x == 0 && threadIdx.x == 0) g_viol = 0u;
    int i = blockIdx.x * 256 + threadIdx.x;
    float4 v = ((const float4*)W)[i];
    short4 o;
    o.x = ((__hip_bfloat16_raw)__float2bfloat16(v.x)).x;
    o.y = ((__hip_bfloat16_raw)__float2bfloat16(v.y)).x;
    o.z = ((__hip_bfloat16_raw)__float2bfloat16(v.z)).x;
    o.w = ((__hip_bfloat16_raw)__float2bfloat16(v.w)).x;
    ((short4*)g_Wb)[i] = o;
}

// ---------- f = pooled @ W^T + b via bf16 MFMA (M=4096, N=768, K=768) ----------
__global__ __launch_bounds__(256) void fw_mfma_kernel(const float* __restrict__ bias) {
    __shared__ short lA[128 * 32];
    __shared__ short lB[128 * 32];
    const int bm = blockIdx.y * 128;
    const int bn = blockIdx.x * 128;

    const int tid  = threadIdx.x;
    const int wave = tid >> 6, lane = tid & 63;
    const int wr = wave >> 1, wc = wave & 1;

    const short* A = (const short*)g_pooledb;
    const short* Bt = (const short*)g_Wb;

    const int c0 = wave * 2, c1 = wave * 2 + 1;
    const int srow = lane >> 2;
    const int scol = (lane & 3) * 8;

    f32x4 acc[4][4];
#pragma unroll
    for (int m = 0; m < 4; ++m)
#pragma unroll
        for (int n = 0; n < 4; ++n) acc[m][n] = (f32x4){0.f, 0.f, 0.f, 0.f};

    for (int k0 = 0; k0 < Dq; k0 += 32) {
        GLDS16(A  + (size_t)(bm + c0 * 16 + srow) * Dq + k0 + scol, lA + c0 * 512);
        GLDS16(A  + (size_t)(bm + c1 * 16 + srow) * Dq + k0 + scol, lA + c1 * 512);
        GLDS16(Bt + (size_t)(bn + c0 * 16 + srow) * Dq + k0 + scol, lB + c0 * 512);
        GLDS16(Bt + (size_t)(bn + c1 * 16 + srow) * Dq + k0 + scol, lB + c1 * 512);
        __syncthreads();

        bf16x8 af[4], bfr[4];
#pragma unroll
        for (int m = 0; m < 4; ++m) {
            int row = wr * 64 + m * 16 + (lane & 15);
            af[m] = *(const bf16x8*)(lA + row * 32 + (lane >> 4) * 8);
        }
#pragma unroll
        for (int n = 0; n < 4; ++n) {
            int row = wc * 64 + n * 16 + (lane & 15);
            bfr[n] = *(const bf16x8*)(lB + row * 32 + (lane >> 4) * 8);
        }
#pragma unroll
        for (int m = 0; m < 4; ++m)
#pragma unroll
            for (int n = 0; n < 4; ++n)
                acc[m][n] = __builtin_amdgcn_mfma_f32_16x16x32_bf16(af[m], bfr[n], acc[m][n], 0, 0, 0);
        __syncthreads();
    }

#pragma unroll
    for (int m = 0; m < 4; ++m) {
        int rowb = bm + wr * 64 + m * 16 + (lane >> 4) * 4;
#pragma unroll
        for (int n = 0; n < 4; ++n) {
            int col = bn + wc * 64 + n * 16 + (lane & 15);
            float bc = bias[col];
#pragma unroll
            for (int j = 0; j < 4; ++j)
                g_f[(size_t)(rowb + j) * Dq + col] = acc[m][n][j] + bc;
        }
    }
}

// ---------- row-normalize -> bf16, one wave per row ----------
__global__ __launch_bounds__(256) void normalize_kernel() {
    int row  = (int)((blockIdx.x * blockDim.x + threadIdx.x) >> 6);
    int lane = threadIdx.x & 63;
    if (row >= Nq) return;
    float ss = 0.f;
    float v[Dq / 64];
#pragma unroll
    for (int j = 0; j < Dq / 64; ++j) { v[j] = g_f[(size_t)row * Dq + j * 64 + lane]; ss += v[j] * v[j]; }
#pragma unroll
    for (int o = 32; o > 0; o >>= 1) ss += __shfl_xor(ss, o, 64);
    float rn = 1.f / sqrtf(ss);
#pragma unroll
    for (int j = 0; j < Dq / 64; ++j)
        g_fb[(size_t)row * Dq + j * 64 + lane] = __float2bfloat16(v[j] * rn);
}

// ---------- sim = fb @ fb^T via bf16 MFMA; epilogue counts sim>0.9 non-label ----------
__global__ __launch_bounds__(256) void sim_mfma_kernel() {
    __shared__ short lA[128 * 32];
    __shared__ short lB[128 * 32];

    int t = blockIdx.x;
    int bi = 0, rem = t;
    while (rem >= (32 - bi)) { rem -= (32 - bi); ++bi; }
    int bj = bi + rem;
    int bm = bi * 128, bn = bj * 128;

    const int tid  = threadIdx.x;
    const int wave = tid >> 6, lane = tid & 63;
    const int wr = wave >> 1, wc = wave & 1;

    const short* fb = (const short*)g_fb;

    const int c0 = wave * 2, c1 = wave * 2 + 1;
    const int srow = lane >> 2;
    const int scol = (lane & 3) * 8;

    f32x4 acc[4][4];
#pragma unroll
    for (int m = 0; m < 4; ++m)
#pragma unroll
        for (int n = 0; n < 4; ++n) acc[m][n] = (f32x4){0.f, 0.f, 0.f, 0.f};

    for (int k0 = 0; k0 < Dq; k0 += 32) {
        GLDS16(fb + (size_t)(bm + c0 * 16 + srow) * Dq + k0 + scol, lA + c0 * 512);
        GLDS16(fb + (size_t)(bm + c1 * 16 + srow) * Dq + k0 + scol, lA + c1 * 512);
        GLDS16(fb + (size_t)(bn + c0 * 16 + srow) * Dq + k0 + scol, lB + c0 * 512);
        GLDS16(fb + (size_t)(bn + c1 * 16 + srow) * Dq + k0 + scol, lB + c1 * 512);
        __syncthreads();

        bf16x8 af[4], bfr[4];
#pragma unroll
        for (int m = 0; m < 4; ++m) {
            int row = wr * 64 + m * 16 + (lane & 15);
            af[m] = *(const bf16x8*)(lA + row * 32 + (lane >> 4) * 8);
        }
#pragma unroll
        for (int n = 0; n < 4; ++n) {
            int row = wc * 64 + n * 16 + (lane & 15);
            bfr[n] = *(const bf16x8*)(lB + row * 32 + (lane >> 4) * 8);
        }
#pragma unroll
        for (int m = 0; m < 4; ++m)
#pragma unroll
            for (int n = 0; n < 4; ++n)
                acc[m][n] = __builtin_amdgcn_mfma_f32_16x16x32_bf16(af[m], bfr[n], acc[m][n], 0, 0, 0);
        __syncthreads();
    }

    int vio = 0;
#pragma unroll
    for (int m = 0; m < 4; ++m) {
        int rowb = bm + wr * 64 + m * 16 + (lane >> 4) * 4;
#pragma unroll
        for (int n = 0; n < 4; ++n) {
            int col = bn + wc * 64 + n * 16 + (lane & 15);
#pragma unroll
            for (int j = 0; j < 4; ++j) {
                g_sim[(size_t)(rowb + j) * Nq + col] = acc[m][n][j];
                vio += (acc[m][n][j] > 0.9f) && ((((rowb + j) ^ col) & 2047) != 0);
            }
        }
    }
    if (bi != bj) {
#pragma unroll
        for (int m = 0; m < 4; ++m) {
            int rowb = bm + wr * 64 + m * 16 + (lane >> 4) * 4;
#pragma unroll
            for (int n = 0; n < 4; ++n) {
                int col = bn + wc * 64 + n * 16 + (lane & 15);
                *(f32x4*)&g_sim[(size_t)col * Nq + rowb] = acc[m][n];
            }
        }
        vio *= 2;   // mirrored elements violate identically
    }
#pragma unroll
    for (int o = 32; o > 0; o >>= 1) vio += __shfl_xor(vio, o, 64);
    if (lane == 0 && vio > 0) atomicAdd(&g_viol, (unsigned int)vio);
}

// ---------- global k from violation count ----------
__global__ void k_kernel() {
    if (threadIdx.x == 0) {
        long long total = (long long)Nq * 4094LL - (long long)g_viol;
        int k = (int)(total / 8192LL);
        g_kk = k < 1 ? 1 : k;
    }
}

// ---------- per-row top-k logsumexp via register-resident bisection ----------
__global__ __launch_bounds__(256) void lse_kernel() {
    const int i   = blockIdx.x;
    const float* row = g_sim + (size_t)i * Nq;
    const int labi = i & 2047;
    const int tid = threadIdx.x;
    const int wave = tid >> 6, lane = tid & 63;

    // load 16 values/thread as 4x float4 (coalesced 16B/lane)
    float v[16];
    unsigned int safe = 0u;
    int cnt = 0;
    float mx = -1e30f;
#pragma unroll
    for (int q4 = 0; q4 < 4; ++q4) {
        int j0 = q4 * 1024 + tid * 4;
        float4 x4 = *(const float4*)(row + j0);
        float xs[4] = {x4.x, x4.y, x4.z, x4.w};
#pragma unroll
        for (int q = 0; q < 4; ++q) {
            int jj = q4 * 4 + q;
            int j  = j0 + q;
            v[jj] = xs[q];
            bool s = (xs[q] <= 0.9f) && (((j ^ labi) & 2047) != 0);
            if (s) { safe |= (1u << jj); cnt++; mx = fmaxf(mx, xs[q]); }
        }
    }
#pragma unroll
    for (int o = 32; o > 0; o >>= 1) {
        cnt += __shfl_xor(cnt, o, 64);
        mx = fmaxf(mx, __shfl_xor(mx, o, 64));
    }
    __shared__ float smx[4]; __shared__ int scnt[4];
    if (lane == 0) { smx[wave] = mx; scnt[wave] = cnt; }
    __syncthreads();
    mx  = fmaxf(fmaxf(smx[0], smx[1]), fmaxf(smx[2], smx[3]));
    cnt = scnt[0] + scnt[1] + scnt[2] + scnt[3];

    const int k = g_kk;
    const float pos = row[(i + Bq) & (Nq - 1)];
    const float mxs = (cnt > 0) ? mx : -10.0f;
    const float ml  = fmaxf(pos, mxs) / TEMPq;

    // bisection for the k-th largest safe value: invariant C(lo) > k >= C(hi)
    float lo = -1.0f, hi = 0.9f;
    int c_hi = 0;
    const bool need_bisect = (cnt > k);
    __shared__ int sred[2][4];
    if (need_bisect) {
        for (int it = 0; it < 26; ++it) {
            float mid = 0.5f * (lo + hi);
            int c = 0;
#pragma unroll
            for (int jj = 0; jj < 16; ++jj)
                c += (int)(((safe >> jj) & 1u) && (v[jj] > mid));
#pragma unroll
            for (int o = 32; o > 0; o >>= 1) c += __shfl_xor(c, o, 64);
            if (lane == 0) sred[it & 1][wave] = c;
            __syncthreads();
            c = sred[it & 1][0] + sred[it & 1][1] + sred[it & 1][2] + sred[it & 1][3];
            if (c > k) lo = mid; else { hi = mid; c_hi = c; }
        }
    }

    // sum exp over kept values; boundary interval (lo, hi] apportioned
    float shi = 0.f, st = 0.f; int nt = 0;
#pragma unroll
    for (int jj = 0; jj < 16; ++jj) {
        if (!((safe >> jj) & 1u)) continue;
        float x = v[jj];
        float ev = expf(x / TEMPq - ml);
        if (!need_bisect) { shi += ev; }
        else if (x > hi)  { shi += ev; }
        else if (x > lo)  { st += ev; nt++; }
    }
#pragma unroll
    for (int o = 32; o > 0; o >>= 1) {
        shi += __shfl_xor(shi, o, 64);
        st  += __shfl_xor(st,  o, 64);
        nt  += __shfl_xor(nt,  o, 64);
    }
    __shared__ float sA[4], sB[4]; __shared__ int sC[4];
    if (lane == 0) { sA[wave] = shi; sB[wave] = st; sC[wave] = nt; }
    __syncthreads();
    if (tid == 0) {
        float Shi = sA[0] + sA[1] + sA[2] + sA[3];
        float St  = sB[0] + sB[1] + sB[2] + sB[3];
        int   Nt  = sC[0] + sC[1] + sC[2] + sC[3];
        float S = expf(pos / TEMPq - ml) + Shi;
        if (need_bisect && c_hi < k && Nt > 0)
            S += St * (float)(k - c_hi) / (float)Nt;
        g_rowloss[i] = (logf(S) + ml) - pos / TEMPq;
    }
}

// ---------- final mean ----------
__global__ __launch_bounds__(256) void loss_kernel(float* __restrict__ out) {
    float s = 0.f;
    for (int i = threadIdx.x; i < Nq; i += 256) s += g_rowloss[i];
    __shared__ float sm[256];
    sm[threadIdx.x] = s; __syncthreads();
    for (int o = 128; o > 0; o >>= 1) {
        if (threadIdx.x < o) sm[threadIdx.x] += sm[threadIdx.x + o];
        __syncthreads();
    }
    if (threadIdx.x == 0) out[0] = sm[0] / (float)Nq;
}

extern "C" void kernel_launch(void* const* d_in, const int* in_sizes, int n_in,
                              void* d_out, int out_size, void* d_ws, size_t ws_size,
                              hipStream_t stream) {
    const float* z         = (const float*)d_in[0];
    const float* query     = (const float*)d_in[3];
    const float* attn_temp = (const float*)d_in[4];
    const float* W         = (const float*)d_in[5];
    const float* bias      = (const float*)d_in[6];
    float* out = (float*)d_out;

    pool_fused_kernel<<<Nq / 4, 256, 0, stream>>>(z, query, attn_temp);
    wconv_kernel<<<(Dq * Dq / 4) / 256, 256, 0, stream>>>(W);
    fw_mfma_kernel<<<dim3(Dq / 128, Nq / 128), 256, 0, stream>>>(bias);
    normalize_kernel<<<Nq / 4, 256, 0, stream>>>();
    sim_mfma_kernel<<<(32 * 33) / 2, 256, 0, stream>>>();
    k_kernel<<<1, 64, 0, stream>>>();
    lse_kernel<<<Nq, 256, 0, stream>>>();
    loss_kernel<<<1, 256, 0, stream>>>(out);
}

// Round 5
// 133.035 us; speedup vs baseline: 4.0529x; 1.2097x over previous
//
#include <hip/hip_runtime.h>
#include <hip/hip_bf16.h>
#include <math.h>

#define Bq   2048
#define Cq   8
#define Dq   768
#define NROW 16384      // B*C per half
#define NTOT 32768      // 2*B*C
#define Nq   4096       // 2*B rows of f
#define TEMPq 0.07f

typedef __attribute__((ext_vector_type(8))) short bf16x8;
typedef __attribute__((ext_vector_type(4))) float f32x4;

// persistent device scratch (fully overwritten every call -> deterministic)
__device__ __hip_bfloat16 g_pooledb[(size_t)Nq * Dq];
__device__ __hip_bfloat16 g_Wb[(size_t)Dq * Dq];
__device__ float          g_f[(size_t)Nq * Dq];
__device__ __hip_bfloat16 g_fb[(size_t)Nq * Dq];
__device__ float          g_sim[(size_t)Nq * Nq];
__device__ unsigned int   g_viol;
__device__ int            g_kk;
__device__ float          g_rowloss[Nq];

#define GLDS16(src, dst) __builtin_amdgcn_global_load_lds( \
    (const __attribute__((address_space(1))) void*)(src),  \
    (__attribute__((address_space(3))) void*)(dst), 16, 0, 0)

// ---------- fused scores + segment softmax + pooling: one wave per segment ----------
// float4 (16B/lane) loads of z; lane covers 4 consecutive cols, 3 j-iterations.
__global__ __launch_bounds__(256) void pool_fused_kernel(const float* __restrict__ z,
                                                         const float* __restrict__ query,
                                                         const float* __restrict__ attn_temp) {
    int seg  = (int)((blockIdx.x * blockDim.x + threadIdx.x) >> 6);
    int lane = threadIdx.x & 63;
    if (seg >= Nq) return;
    int half = seg >> 11;
    int b    = seg & 2047;
    int baseRow = half * NROW + b * Cq;
    float invt = 1.f / attn_temp[0];

    float4 q4[3];
#pragma unroll
    for (int j = 0; j < 3; ++j) q4[j] = *(const float4*)(query + j * 256 + lane * 4);

    float4 v4[Cq][3];
    float s[Cq];
#pragma unroll
    for (int c = 0; c < Cq; ++c) {
        const float* zr = z + (size_t)(baseRow + c) * Dq;
        float acc = 0.f;
#pragma unroll
        for (int j = 0; j < 3; ++j) {
            float4 vz = *(const float4*)(zr + j * 256 + lane * 4);
            v4[c][j] = vz;
            acc += vz.x * q4[j].x + vz.y * q4[j].y + vz.z * q4[j].z + vz.w * q4[j].w;
        }
#pragma unroll
        for (int o = 32; o > 0; o >>= 1) acc += __shfl_xor(acc, o, 64);
        s[c] = acc * invt;
    }
    float m = s[0];
#pragma unroll
    for (int c = 1; c < Cq; ++c) m = fmaxf(m, s[c]);
    float e[Cq], denom = 0.f;
#pragma unroll
    for (int c = 0; c < Cq; ++c) { e[c] = expf(s[c] - m); denom += e[c]; }
    float inv = 1.f / (denom + 1e-8f);
#pragma unroll
    for (int j = 0; j < 3; ++j) {
        float4 acc = {0.f, 0.f, 0.f, 0.f};
#pragma unroll
        for (int c = 0; c < Cq; ++c) {
            acc.x += v4[c][j].x * e[c];
            acc.y += v4[c][j].y * e[c];
            acc.z += v4[c][j].z * e[c];
            acc.w += v4[c][j].w * e[c];
        }
        short4 o;
        o.x = ((__hip_bfloat16_raw)__float2bfloat16(acc.x * inv)).x;
        o.y = ((__hip_bfloat16_raw)__float2bfloat16(acc.y * inv)).x;
        o.z = ((__hip_bfloat16_raw)__float2bfloat16(acc.z * inv)).x;
        o.w = ((__hip_bfloat16_raw)__float2bfloat16(acc.w * inv)).x;
        *(short4*)((short*)g_pooledb + (size_t)seg * Dq + j * 256 + lane * 4) = o;
    }
}

// ---------- W -> bf16, also zero the violation counter ----------
__global__ __launch_bounds__(256) void wconv_kernel(const float* __restrict__ W) {
    if (blockIdx.x == 0 && threadIdx.x == 0) g_viol = 0u;
    int i = blockIdx.x * 256 + threadIdx.x;
    float4 v = ((const float4*)W)[i];
    short4 o;
    o.x = ((__hip_bfloat16_raw)__float2bfloat16(v.x)).x;
    o.y = ((__hip_bfloat16_raw)__float2bfloat16(v.y)).x;
    o.z = ((__hip_bfloat16_raw)__float2bfloat16(v.z)).x;
    o.w = ((__hip_bfloat16_raw)__float2bfloat16(v.w)).x;
    ((short4*)g_Wb)[i] = o;
}

// ---------- f = pooled @ W^T + b via bf16 MFMA (M=4096, N=768, K=768) ----------
__global__ __launch_bounds__(256) void fw_mfma_kernel(const float* __restrict__ bias) {
    __shared__ short lA[128 * 32];
    __shared__ short lB[128 * 32];
    const int bm = blockIdx.y * 128;
    const int bn = blockIdx.x * 128;

    const int tid  = threadIdx.x;
    const int wave = tid >> 6, lane = tid & 63;
    const int wr = wave >> 1, wc = wave & 1;

    const short* A = (const short*)g_pooledb;
    const short* Bt = (const short*)g_Wb;

    const int c0 = wave * 2, c1 = wave * 2 + 1;
    const int srow = lane >> 2;
    const int scol = (lane & 3) * 8;

    f32x4 acc[4][4];
#pragma unroll
    for (int m = 0; m < 4; ++m)
#pragma unroll
        for (int n = 0; n < 4; ++n) acc[m][n] = (f32x4){0.f, 0.f, 0.f, 0.f};

    for (int k0 = 0; k0 < Dq; k0 += 32) {
        GLDS16(A  + (size_t)(bm + c0 * 16 + srow) * Dq + k0 + scol, lA + c0 * 512);
        GLDS16(A  + (size_t)(bm + c1 * 16 + srow) * Dq + k0 + scol, lA + c1 * 512);
        GLDS16(Bt + (size_t)(bn + c0 * 16 + srow) * Dq + k0 + scol, lB + c0 * 512);
        GLDS16(Bt + (size_t)(bn + c1 * 16 + srow) * Dq + k0 + scol, lB + c1 * 512);
        __syncthreads();

        bf16x8 af[4], bfr[4];
#pragma unroll
        for (int m = 0; m < 4; ++m) {
            int row = wr * 64 + m * 16 + (lane & 15);
            af[m] = *(const bf16x8*)(lA + row * 32 + (lane >> 4) * 8);
        }
#pragma unroll
        for (int n = 0; n < 4; ++n) {
            int row = wc * 64 + n * 16 + (lane & 15);
            bfr[n] = *(const bf16x8*)(lB + row * 32 + (lane >> 4) * 8);
        }
#pragma unroll
        for (int m = 0; m < 4; ++m)
#pragma unroll
            for (int n = 0; n < 4; ++n)
                acc[m][n] = __builtin_amdgcn_mfma_f32_16x16x32_bf16(af[m], bfr[n], acc[m][n], 0, 0, 0);
        __syncthreads();
    }

#pragma unroll
    for (int m = 0; m < 4; ++m) {
        int rowb = bm + wr * 64 + m * 16 + (lane >> 4) * 4;
#pragma unroll
        for (int n = 0; n < 4; ++n) {
            int col = bn + wc * 64 + n * 16 + (lane & 15);
            float bc = bias[col];
#pragma unroll
            for (int j = 0; j < 4; ++j)
                g_f[(size_t)(rowb + j) * Dq + col] = acc[m][n][j] + bc;
        }
    }
}

// ---------- row-normalize -> bf16, one wave per row ----------
__global__ __launch_bounds__(256) void normalize_kernel() {
    int row  = (int)((blockIdx.x * blockDim.x + threadIdx.x) >> 6);
    int lane = threadIdx.x & 63;
    if (row >= Nq) return;
    float ss = 0.f;
    float v[Dq / 64];
#pragma unroll
    for (int j = 0; j < Dq / 64; ++j) { v[j] = g_f[(size_t)row * Dq + j * 64 + lane]; ss += v[j] * v[j]; }
#pragma unroll
    for (int o = 32; o > 0; o >>= 1) ss += __shfl_xor(ss, o, 64);
    float rn = 1.f / sqrtf(ss);
#pragma unroll
    for (int j = 0; j < Dq / 64; ++j)
        g_fb[(size_t)row * Dq + j * 64 + lane] = __float2bfloat16(v[j] * rn);
}

// ---------- sim = fb @ fb^T via bf16 MFMA; epilogue counts sim>0.9 non-label ----------
__global__ __launch_bounds__(256) void sim_mfma_kernel() {
    __shared__ short lA[128 * 32];
    __shared__ short lB[128 * 32];

    int t = blockIdx.x;
    int bi = 0, rem = t;
    while (rem >= (32 - bi)) { rem -= (32 - bi); ++bi; }
    int bj = bi + rem;
    int bm = bi * 128, bn = bj * 128;

    const int tid  = threadIdx.x;
    const int wave = tid >> 6, lane = tid & 63;
    const int wr = wave >> 1, wc = wave & 1;

    const short* fb = (const short*)g_fb;

    const int c0 = wave * 2, c1 = wave * 2 + 1;
    const int srow = lane >> 2;
    const int scol = (lane & 3) * 8;

    f32x4 acc[4][4];
#pragma unroll
    for (int m = 0; m < 4; ++m)
#pragma unroll
        for (int n = 0; n < 4; ++n) acc[m][n] = (f32x4){0.f, 0.f, 0.f, 0.f};

    for (int k0 = 0; k0 < Dq; k0 += 32) {
        GLDS16(fb + (size_t)(bm + c0 * 16 + srow) * Dq + k0 + scol, lA + c0 * 512);
        GLDS16(fb + (size_t)(bm + c1 * 16 + srow) * Dq + k0 + scol, lA + c1 * 512);
        GLDS16(fb + (size_t)(bn + c0 * 16 + srow) * Dq + k0 + scol, lB + c0 * 512);
        GLDS16(fb + (size_t)(bn + c1 * 16 + srow) * Dq + k0 + scol, lB + c1 * 512);
        __syncthreads();

        bf16x8 af[4], bfr[4];
#pragma unroll
        for (int m = 0; m < 4; ++m) {
            int row = wr * 64 + m * 16 + (lane & 15);
            af[m] = *(const bf16x8*)(lA + row * 32 + (lane >> 4) * 8);
        }
#pragma unroll
        for (int n = 0; n < 4; ++n) {
            int row = wc * 64 + n * 16 + (lane & 15);
            bfr[n] = *(const bf16x8*)(lB + row * 32 + (lane >> 4) * 8);
        }
#pragma unroll
        for (int m = 0; m < 4; ++m)
#pragma unroll
            for (int n = 0; n < 4; ++n)
                acc[m][n] = __builtin_amdgcn_mfma_f32_16x16x32_bf16(af[m], bfr[n], acc[m][n], 0, 0, 0);
        __syncthreads();
    }

    int vio = 0;
#pragma unroll
    for (int m = 0; m < 4; ++m) {
        int rowb = bm + wr * 64 + m * 16 + (lane >> 4) * 4;
#pragma unroll
        for (int n = 0; n < 4; ++n) {
            int col = bn + wc * 64 + n * 16 + (lane & 15);
#pragma unroll
            for (int j = 0; j < 4; ++j) {
                g_sim[(size_t)(rowb + j) * Nq + col] = acc[m][n][j];
                vio += (acc[m][n][j] > 0.9f) && ((((rowb + j) ^ col) & 2047) != 0);
            }
        }
    }
    if (bi != bj) {
#pragma unroll
        for (int m = 0; m < 4; ++m) {
            int rowb = bm + wr * 64 + m * 16 + (lane >> 4) * 4;
#pragma unroll
            for (int n = 0; n < 4; ++n) {
                int col = bn + wc * 64 + n * 16 + (lane & 15);
                *(f32x4*)&g_sim[(size_t)col * Nq + rowb] = acc[m][n];
            }
        }
        vio *= 2;   // mirrored elements violate identically
    }
#pragma unroll
    for (int o = 32; o > 0; o >>= 1) vio += __shfl_xor(vio, o, 64);
    if (lane == 0 && vio > 0) atomicAdd(&g_viol, (unsigned int)vio);
}

// ---------- global k from violation count ----------
__global__ void k_kernel() {
    if (threadIdx.x == 0) {
        long long total = (long long)Nq * 4094LL - (long long)g_viol;
        int k = (int)(total / 8192LL);
        g_kk = k < 1 ? 1 : k;
    }
}

// ---------- per-row top-k logsumexp: sentinel values + narrowed-bracket bisection ----------
__global__ __launch_bounds__(256) void lse_kernel() {
    const int i   = blockIdx.x;
    const float* row = g_sim + (size_t)i * Nq;
    const int labi = i & 2047;
    const int tid = threadIdx.x;
    const int wave = tid >> 6, lane = tid & 63;
    const float invT = 1.0f / TEMPq;

    // load 16 values/thread as 4x float4; unsafe slots -> sentinel -2.0
    float v[16];
    int cnt = 0;
    float mx = -1e30f, mn = 1e30f;
#pragma unroll
    for (int q4i = 0; q4i < 4; ++q4i) {
        int j0 = q4i * 1024 + tid * 4;
        float4 x4 = *(const float4*)(row + j0);
        float xs[4] = {x4.x, x4.y, x4.z, x4.w};
#pragma unroll
        for (int q = 0; q < 4; ++q) {
            int jj = q4i * 4 + q;
            int j  = j0 + q;
            bool s = (xs[q] <= 0.9f) && (((j ^ labi) & 2047) != 0);
            if (s) { cnt++; mx = fmaxf(mx, xs[q]); mn = fminf(mn, xs[q]); v[jj] = xs[q]; }
            else v[jj] = -2.0f;
        }
    }
#pragma unroll
    for (int o = 32; o > 0; o >>= 1) {
        cnt += __shfl_xor(cnt, o, 64);
        mx = fmaxf(mx, __shfl_xor(mx, o, 64));
        mn = fminf(mn, __shfl_xor(mn, o, 64));
    }
    __shared__ float smx[4], smn[4]; __shared__ int scnt[4];
    if (lane == 0) { smx[wave] = mx; smn[wave] = mn; scnt[wave] = cnt; }
    __syncthreads();
    mx  = fmaxf(fmaxf(smx[0], smx[1]), fmaxf(smx[2], smx[3]));
    mn  = fminf(fminf(smn[0], smn[1]), fminf(smn[2], smn[3]));
    cnt = scnt[0] + scnt[1] + scnt[2] + scnt[3];

    const int k = g_kk;
    const float pos = row[(i + Bq) & (Nq - 1)];
    const float mxs = (cnt > 0) ? mx : -10.0f;
    const float ml  = fmaxf(pos, mxs) * invT;

    // bisection for the k-th largest safe value on [mn-1e-3, mx]
    // invariant: C(lo) > k >= C(hi), where C(x) = #{safe v > x}
    float lo = mn - 1e-3f, hi = mx;
    int c_hi = 0;
    const bool need_bisect = (cnt > k);
    __shared__ int sred[2][4];
    if (need_bisect) {
        for (int it = 0; it < 12; ++it) {
            float mid = 0.5f * (lo + hi);
            int c = 0;
#pragma unroll
            for (int jj = 0; jj < 16; ++jj) c += (int)(v[jj] > mid);
#pragma unroll
            for (int o = 32; o > 0; o >>= 1) c += __shfl_xor(c, o, 64);
            if (lane == 0) sred[it & 1][wave] = c;
            __syncthreads();
            c = sred[it & 1][0] + sred[it & 1][1] + sred[it & 1][2] + sred[it & 1][3];
            if (c > k) lo = mid; else { hi = mid; c_hi = c; }
        }
    }

    // sum exp over kept values; boundary interval (lo, hi] apportioned.
    // sentinels (-2.0) fall below lo (> mn-1e-3 > -1.5) -> excluded naturally.
    float shi = 0.f, st = 0.f; int nt = 0;
#pragma unroll
    for (int jj = 0; jj < 16; ++jj) {
        float x = v[jj];
        float ev = __expf(x * invT - ml);   // sentinel exp ~ e-28 -> negligible where counted
        if (!need_bisect) { if (x > -1.5f) shi += ev; }
        else if (x > hi)  { shi += ev; }
        else if (x > lo)  { st += ev; nt++; }
    }
#pragma unroll
    for (int o = 32; o > 0; o >>= 1) {
        shi += __shfl_xor(shi, o, 64);
        st  += __shfl_xor(st,  o, 64);
        nt  += __shfl_xor(nt,  o, 64);
    }
    __shared__ float sA[4], sB[4]; __shared__ int sC[4];
    if (lane == 0) { sA[wave] = shi; sB[wave] = st; sC[wave] = nt; }
    __syncthreads();
    if (tid == 0) {
        float Shi = sA[0] + sA[1] + sA[2] + sA[3];
        float St  = sB[0] + sB[1] + sB[2] + sB[3];
        int   Nt  = sC[0] + sC[1] + sC[2] + sC[3];
        float S = __expf(pos * invT - ml) + Shi;
        if (need_bisect && c_hi < k && Nt > 0)
            S += St * (float)(k - c_hi) / (float)Nt;
        g_rowloss[i] = (logf(S) + ml) - pos * invT;
    }
}

// ---------- final mean ----------
__global__ __launch_bounds__(256) void loss_kernel(float* __restrict__ out) {
    float s = 0.f;
    for (int i = threadIdx.x; i < Nq; i += 256) s += g_rowloss[i];
    __shared__ float sm[256];
    sm[threadIdx.x] = s; __syncthreads();
    for (int o = 128; o > 0; o >>= 1) {
        if (threadIdx.x < o) sm[threadIdx.x] += sm[threadIdx.x + o];
        __syncthreads();
    }
    if (threadIdx.x == 0) out[0] = sm[0] / (float)Nq;
}

extern "C" void kernel_launch(void* const* d_in, const int* in_sizes, int n_in,
                              void* d_out, int out_size, void* d_ws, size_t ws_size,
                              hipStream_t stream) {
    const float* z         = (const float*)d_in[0];
    const float* query     = (const float*)d_in[3];
    const float* attn_temp = (const float*)d_in[4];
    const float* W         = (const float*)d_in[5];
    const float* bias      = (const float*)d_in[6];
    float* out = (float*)d_out;

    pool_fused_kernel<<<Nq / 4, 256, 0, stream>>>(z, query, attn_temp);
    wconv_kernel<<<(Dq * Dq / 4) / 256, 256, 0, stream>>>(W);
    fw_mfma_kernel<<<dim3(Dq / 128, Nq / 128), 256, 0, stream>>>(bias);
    normalize_kernel<<<Nq / 4, 256, 0, stream>>>();
    sim_mfma_kernel<<<(32 * 33) / 2, 256, 0, stream>>>();
    k_kernel<<<1, 64, 0, stream>>>();
    lse_kernel<<<Nq, 256, 0, stream>>>();
    loss_kernel<<<1, 256, 0, stream>>>(out);
}

// Round 6
// 129.352 us; speedup vs baseline: 4.1683x; 1.0285x over previous
//
#include <hip/hip_runtime.h>
#include <hip/hip_bf16.h>
#include <math.h>

#define Bq   2048
#define Cq   8
#define Dq   768
#define NROW 16384      // B*C per half
#define NTOT 32768      // 2*B*C
#define Nq   4096       // 2*B rows of f
#define TEMPq 0.07f

typedef __attribute__((ext_vector_type(8))) short bf16x8;
typedef __attribute__((ext_vector_type(4))) float f32x4;

// persistent device scratch (fully overwritten every call -> deterministic)
__device__ __hip_bfloat16 g_pooledb[(size_t)Nq * Dq];
__device__ __hip_bfloat16 g_Wb[(size_t)Dq * Dq];
__device__ float          g_f[(size_t)Nq * Dq];
__device__ __hip_bfloat16 g_fb[(size_t)Nq * Dq];
__device__ float          g_sim[(size_t)Nq * Nq];
__device__ unsigned int   g_viol;
__device__ float          g_rowloss[Nq];

#define GLDS16(src, dst) __builtin_amdgcn_global_load_lds( \
    (const __attribute__((address_space(1))) void*)(src),  \
    (__attribute__((address_space(3))) void*)(dst), 16, 0, 0)

// ---------- fused scores + segment softmax + pooling: one wave per segment ----------
__global__ __launch_bounds__(256) void pool_fused_kernel(const float* __restrict__ z,
                                                         const float* __restrict__ query,
                                                         const float* __restrict__ attn_temp) {
    int seg  = (int)((blockIdx.x * blockDim.x + threadIdx.x) >> 6);
    int lane = threadIdx.x & 63;
    if (seg >= Nq) return;
    int half = seg >> 11;
    int b    = seg & 2047;
    int baseRow = half * NROW + b * Cq;
    float invt = 1.f / attn_temp[0];

    float4 q4[3];
#pragma unroll
    for (int j = 0; j < 3; ++j) q4[j] = *(const float4*)(query + j * 256 + lane * 4);

    float4 v4[Cq][3];
    float s[Cq];
#pragma unroll
    for (int c = 0; c < Cq; ++c) {
        const float* zr = z + (size_t)(baseRow + c) * Dq;
        float acc = 0.f;
#pragma unroll
        for (int j = 0; j < 3; ++j) {
            float4 vz = *(const float4*)(zr + j * 256 + lane * 4);
            v4[c][j] = vz;
            acc += vz.x * q4[j].x + vz.y * q4[j].y + vz.z * q4[j].z + vz.w * q4[j].w;
        }
#pragma unroll
        for (int o = 32; o > 0; o >>= 1) acc += __shfl_xor(acc, o, 64);
        s[c] = acc * invt;
    }
    float m = s[0];
#pragma unroll
    for (int c = 1; c < Cq; ++c) m = fmaxf(m, s[c]);
    float e[Cq], denom = 0.f;
#pragma unroll
    for (int c = 0; c < Cq; ++c) { e[c] = expf(s[c] - m); denom += e[c]; }
    float inv = 1.f / (denom + 1e-8f);
#pragma unroll
    for (int j = 0; j < 3; ++j) {
        float4 acc = {0.f, 0.f, 0.f, 0.f};
#pragma unroll
        for (int c = 0; c < Cq; ++c) {
            acc.x += v4[c][j].x * e[c];
            acc.y += v4[c][j].y * e[c];
            acc.z += v4[c][j].z * e[c];
            acc.w += v4[c][j].w * e[c];
        }
        short4 o;
        o.x = ((__hip_bfloat16_raw)__float2bfloat16(acc.x * inv)).x;
        o.y = ((__hip_bfloat16_raw)__float2bfloat16(acc.y * inv)).x;
        o.z = ((__hip_bfloat16_raw)__float2bfloat16(acc.z * inv)).x;
        o.w = ((__hip_bfloat16_raw)__float2bfloat16(acc.w * inv)).x;
        *(short4*)((short*)g_pooledb + (size_t)seg * Dq + j * 256 + lane * 4) = o;
    }
}

// ---------- W -> bf16, also zero the violation counter ----------
__global__ __launch_bounds__(256) void wconv_kernel(const float* __restrict__ W) {
    if (blockIdx.x == 0 && threadIdx.x == 0) g_viol = 0u;
    int i = blockIdx.x * 256 + threadIdx.x;
    float4 v = ((const float4*)W)[i];
    short4 o;
    o.x = ((__hip_bfloat16_raw)__float2bfloat16(v.x)).x;
    o.y = ((__hip_bfloat16_raw)__float2bfloat16(v.y)).x;
    o.z = ((__hip_bfloat16_raw)__float2bfloat16(v.z)).x;
    o.w = ((__hip_bfloat16_raw)__float2bfloat16(v.w)).x;
    ((short4*)g_Wb)[i] = o;
}

// ---------- f = pooled @ W^T + b via bf16 MFMA (M=4096, N=768, K=768) ----------
__global__ __launch_bounds__(256) void fw_mfma_kernel(const float* __restrict__ bias) {
    __shared__ short lA[128 * 32];
    __shared__ short lB[128 * 32];
    const int bm = blockIdx.y * 128;
    const int bn = blockIdx.x * 128;

    const int tid  = threadIdx.x;
    const int wave = tid >> 6, lane = tid & 63;
    const int wr = wave >> 1, wc = wave & 1;

    const short* A = (const short*)g_pooledb;
    const short* Bt = (const short*)g_Wb;

    const int c0 = wave * 2, c1 = wave * 2 + 1;
    const int srow = lane >> 2;
    const int scol = (lane & 3) * 8;

    f32x4 acc[4][4];
#pragma unroll
    for (int m = 0; m < 4; ++m)
#pragma unroll
        for (int n = 0; n < 4; ++n) acc[m][n] = (f32x4){0.f, 0.f, 0.f, 0.f};

    for (int k0 = 0; k0 < Dq; k0 += 32) {
        GLDS16(A  + (size_t)(bm + c0 * 16 + srow) * Dq + k0 + scol, lA + c0 * 512);
        GLDS16(A  + (size_t)(bm + c1 * 16 + srow) * Dq + k0 + scol, lA + c1 * 512);
        GLDS16(Bt + (size_t)(bn + c0 * 16 + srow) * Dq + k0 + scol, lB + c0 * 512);
        GLDS16(Bt + (size_t)(bn + c1 * 16 + srow) * Dq + k0 + scol, lB + c1 * 512);
        __syncthreads();

        bf16x8 af[4], bfr[4];
#pragma unroll
        for (int m = 0; m < 4; ++m) {
            int row = wr * 64 + m * 16 + (lane & 15);
            af[m] = *(const bf16x8*)(lA + row * 32 + (lane >> 4) * 8);
        }
#pragma unroll
        for (int n = 0; n < 4; ++n) {
            int row = wc * 64 + n * 16 + (lane & 15);
            bfr[n] = *(const bf16x8*)(lB + row * 32 + (lane >> 4) * 8);
        }
#pragma unroll
        for (int m = 0; m < 4; ++m)
#pragma unroll
            for (int n = 0; n < 4; ++n)
                acc[m][n] = __builtin_amdgcn_mfma_f32_16x16x32_bf16(af[m], bfr[n], acc[m][n], 0, 0, 0);
        __syncthreads();
    }

#pragma unroll
    for (int m = 0; m < 4; ++m) {
        int rowb = bm + wr * 64 + m * 16 + (lane >> 4) * 4;
#pragma unroll
        for (int n = 0; n < 4; ++n) {
            int col = bn + wc * 64 + n * 16 + (lane & 15);
            float bc = bias[col];
#pragma unroll
            for (int j = 0; j < 4; ++j)
                g_f[(size_t)(rowb + j) * Dq + col] = acc[m][n][j] + bc;
        }
    }
}

// ---------- row-normalize -> bf16, one wave per row ----------
__global__ __launch_bounds__(256) void normalize_kernel() {
    int row  = (int)((blockIdx.x * blockDim.x + threadIdx.x) >> 6);
    int lane = threadIdx.x & 63;
    if (row >= Nq) return;
    float ss = 0.f;
    float v[Dq / 64];
#pragma unroll
    for (int j = 0; j < Dq / 64; ++j) { v[j] = g_f[(size_t)row * Dq + j * 64 + lane]; ss += v[j] * v[j]; }
#pragma unroll
    for (int o = 32; o > 0; o >>= 1) ss += __shfl_xor(ss, o, 64);
    float rn = 1.f / sqrtf(ss);
#pragma unroll
    for (int j = 0; j < Dq / 64; ++j)
        g_fb[(size_t)row * Dq + j * 64 + lane] = __float2bfloat16(v[j] * rn);
}

// ---------- sim = fb @ fb^T via bf16 MFMA; epilogue counts sim>0.9 non-label ----------
__global__ __launch_bounds__(256) void sim_mfma_kernel() {
    __shared__ short lA[128 * 32];
    __shared__ short lB[128 * 32];

    int t = blockIdx.x;
    int bi = 0, rem = t;
    while (rem >= (32 - bi)) { rem -= (32 - bi); ++bi; }
    int bj = bi + rem;
    int bm = bi * 128, bn = bj * 128;

    const int tid  = threadIdx.x;
    const int wave = tid >> 6, lane = tid & 63;
    const int wr = wave >> 1, wc = wave & 1;

    const short* fb = (const short*)g_fb;

    const int c0 = wave * 2, c1 = wave * 2 + 1;
    const int srow = lane >> 2;
    const int scol = (lane & 3) * 8;

    f32x4 acc[4][4];
#pragma unroll
    for (int m = 0; m < 4; ++m)
#pragma unroll
        for (int n = 0; n < 4; ++n) acc[m][n] = (f32x4){0.f, 0.f, 0.f, 0.f};

    for (int k0 = 0; k0 < Dq; k0 += 32) {
        GLDS16(fb + (size_t)(bm + c0 * 16 + srow) * Dq + k0 + scol, lA + c0 * 512);
        GLDS16(fb + (size_t)(bm + c1 * 16 + srow) * Dq + k0 + scol, lA + c1 * 512);
        GLDS16(fb + (size_t)(bn + c0 * 16 + srow) * Dq + k0 + scol, lB + c0 * 512);
        GLDS16(fb + (size_t)(bn + c1 * 16 + srow) * Dq + k0 + scol, lB + c1 * 512);
        __syncthreads();

        bf16x8 af[4], bfr[4];
#pragma unroll
        for (int m = 0; m < 4; ++m) {
            int row = wr * 64 + m * 16 + (lane & 15);
            af[m] = *(const bf16x8*)(lA + row * 32 + (lane >> 4) * 8);
        }
#pragma unroll
        for (int n = 0; n < 4; ++n) {
            int row = wc * 64 + n * 16 + (lane & 15);
            bfr[n] = *(const bf16x8*)(lB + row * 32 + (lane >> 4) * 8);
        }
#pragma unroll
        for (int m = 0; m < 4; ++m)
#pragma unroll
            for (int n = 0; n < 4; ++n)
                acc[m][n] = __builtin_amdgcn_mfma_f32_16x16x32_bf16(af[m], bfr[n], acc[m][n], 0, 0, 0);
        __syncthreads();
    }

    int vio = 0;
#pragma unroll
    for (int m = 0; m < 4; ++m) {
        int rowb = bm + wr * 64 + m * 16 + (lane >> 4) * 4;
#pragma unroll
        for (int n = 0; n < 4; ++n) {
            int col = bn + wc * 64 + n * 16 + (lane & 15);
#pragma unroll
            for (int j = 0; j < 4; ++j) {
                g_sim[(size_t)(rowb + j) * Nq + col] = acc[m][n][j];
                vio += (acc[m][n][j] > 0.9f) && ((((rowb + j) ^ col) & 2047) != 0);
            }
        }
    }
    if (bi != bj) {
#pragma unroll
        for (int m = 0; m < 4; ++m) {
            int rowb = bm + wr * 64 + m * 16 + (lane >> 4) * 4;
#pragma unroll
            for (int n = 0; n < 4; ++n) {
                int col = bn + wc * 64 + n * 16 + (lane & 15);
                *(f32x4*)&g_sim[(size_t)col * Nq + rowb] = acc[m][n];
            }
        }
        vio *= 2;   // mirrored elements violate identically
    }
#pragma unroll
    for (int o = 32; o > 0; o >>= 1) vio += __shfl_xor(vio, o, 64);
    if (lane == 0 && vio > 0) atomicAdd(&g_viol, (unsigned int)vio);
}

// ---------- per-row top-k logsumexp: ONE WAVE PER ROW, ballot-popcount bisection ----------
// No LDS, no barriers. 64 values/lane; counts via __ballot+popcll land wave-uniform
// in SGPRs (scalar pipe co-issues with the VALU compares).
__global__ __launch_bounds__(256) void lse_kernel() {
    const int row_id = (int)((blockIdx.x * blockDim.x + threadIdx.x) >> 6);  // 4 rows/block
    const int lane = threadIdx.x & 63;
    const float* row = g_sim + (size_t)row_id * Nq;
    const int labi = row_id & 2047;
    const float invT = 1.0f / TEMPq;

    // k from violation count (wave-uniform scalar math)
    long long total = (long long)Nq * 4094LL - (long long)g_viol;
    int k = (int)(total / 8192LL);
    if (k < 1) k = 1;

    // load 64 values/lane; unsafe -> sentinel -2 (below any cosine sim)
    float v[64];
    float mx = -1e30f, mn = 1e30f;
    int cnt = 0;
#pragma unroll
    for (int q = 0; q < 16; ++q) {
        int j0 = q * 256 + lane * 4;
        float4 x4 = *(const float4*)(row + j0);
        float xs[4] = {x4.x, x4.y, x4.z, x4.w};
#pragma unroll
        for (int s = 0; s < 4; ++s) {
            int jj = q * 4 + s;
            int j  = j0 + s;
            bool sf = (xs[s] <= 0.9f) && (((j ^ labi) & 2047) != 0);
            float val = sf ? xs[s] : -2.0f;
            v[jj] = val;
            mx = fmaxf(mx, val);
            mn = fminf(mn, sf ? xs[s] : 2.0f);
            cnt += (int)__popcll(__ballot(sf));   // wave-total, uniform
        }
    }
#pragma unroll
    for (int o = 32; o > 0; o >>= 1) {
        mx = fmaxf(mx, __shfl_xor(mx, o, 64));
        mn = fminf(mn, __shfl_xor(mn, o, 64));
    }

    const float pos = row[(row_id + Bq) & (Nq - 1)];   // same addr all lanes -> broadcast
    const float mxs = (cnt > 0) ? mx : -10.0f;
    const float ml  = fmaxf(pos, mxs) * invT;

    // bisection for k-th largest on [mn-1e-3, mx]; C(lo) > k >= C(hi)
    float lo = mn - 1e-3f, hi = mx;
    int c_hi = 0;
    const bool need = (cnt > k);
    if (need) {
        for (int it = 0; it < 12; ++it) {
            float mid = 0.5f * (lo + hi);
            int c = 0;
#pragma unroll
            for (int jj = 0; jj < 64; ++jj)
                c += (int)__popcll(__ballot(v[jj] > mid));
            if (c > k) lo = mid; else { hi = mid; c_hi = c; }
        }
    }

    // exp sum; boundary bin (lo, hi] apportioned. Sentinels < lo always.
    float shi = 0.f, st = 0.f; int nt = 0;
#pragma unroll
    for (int jj = 0; jj < 64; ++jj) {
        float x = v[jj];
        float ev = __expf(x * invT - ml);
        if (!need)       { if (x > -1.5f) shi += ev; }
        else if (x > hi) { shi += ev; }
        else if (x > lo) { st += ev; nt++; }
    }
#pragma unroll
    for (int o = 32; o > 0; o >>= 1) {
        shi += __shfl_xor(shi, o, 64);
        st  += __shfl_xor(st,  o, 64);
        nt  += __shfl_xor(nt,  o, 64);
    }
    if (lane == 0) {
        float S = __expf(pos * invT - ml) + shi;
        if (need && c_hi < k && nt > 0)
            S += st * (float)(k - c_hi) / (float)nt;
        g_rowloss[row_id] = (logf(S) + ml) - pos * invT;
    }
}

// ---------- final mean ----------
__global__ __launch_bounds__(256) void loss_kernel(float* __restrict__ out) {
    float s = 0.f;
    for (int i = threadIdx.x; i < Nq; i += 256) s += g_rowloss[i];
    __shared__ float sm[256];
    sm[threadIdx.x] = s; __syncthreads();
    for (int o = 128; o > 0; o >>= 1) {
        if (threadIdx.x < o) sm[threadIdx.x] += sm[threadIdx.x + o];
        __syncthreads();
    }
    if (threadIdx.x == 0) out[0] = sm[0] / (float)Nq;
}

extern "C" void kernel_launch(void* const* d_in, const int* in_sizes, int n_in,
                              void* d_out, int out_size, void* d_ws, size_t ws_size,
                              hipStream_t stream) {
    const float* z         = (const float*)d_in[0];
    const float* query     = (const float*)d_in[3];
    const float* attn_temp = (const float*)d_in[4];
    const float* W         = (const float*)d_in[5];
    const float* bias      = (const float*)d_in[6];
    float* out = (float*)d_out;

    pool_fused_kernel<<<Nq / 4, 256, 0, stream>>>(z, query, attn_temp);
    wconv_kernel<<<(Dq * Dq / 4) / 256, 256, 0, stream>>>(W);
    fw_mfma_kernel<<<dim3(Dq / 128, Nq / 128), 256, 0, stream>>>(bias);
    normalize_kernel<<<Nq / 4, 256, 0, stream>>>();
    sim_mfma_kernel<<<(32 * 33) / 2, 256, 0, stream>>>();
    lse_kernel<<<Nq / 4, 256, 0, stream>>>();
    loss_kernel<<<1, 256, 0, stream>>>(out);
}

// Round 7
// 121.262 us; speedup vs baseline: 4.4463x; 1.0667x over previous
//
#include <hip/hip_runtime.h>
#include <hip/hip_bf16.h>
#include <math.h>

#define Bq   2048
#define Cq   8
#define Dq   768
#define NROW 16384      // B*C per half
#define NTOT 32768      // 2*B*C
#define Nq   4096       // 2*B rows of f
#define TEMPq 0.07f

typedef __attribute__((ext_vector_type(8))) short bf16x8;
typedef __attribute__((ext_vector_type(4))) float f32x4;
typedef __attribute__((ext_vector_type(8))) _Float16 f16x8;
typedef __attribute__((ext_vector_type(4))) _Float16 f16x4;

// persistent device scratch (fully overwritten every call -> deterministic)
__device__ __hip_bfloat16 g_pooledb[(size_t)Nq * Dq];
__device__ __hip_bfloat16 g_Wb[(size_t)Dq * Dq];
__device__ float          g_f[(size_t)Nq * Dq];
__device__ __hip_bfloat16 g_fb[(size_t)Nq * Dq];
__device__ _Float16       g_simh[(size_t)Nq * Nq];
__device__ unsigned int   g_viol;
__device__ float          g_rowloss[Nq];

#define GLDS16(src, dst) __builtin_amdgcn_global_load_lds( \
    (const __attribute__((address_space(1))) void*)(src),  \
    (__attribute__((address_space(3))) void*)(dst), 16, 0, 0)

// ---------- merged: [blocks 0..1023] fused pool, [1024..1599] W->bf16 ----------
__global__ __launch_bounds__(256) void prep_kernel(const float* __restrict__ z,
                                                   const float* __restrict__ query,
                                                   const float* __restrict__ attn_temp,
                                                   const float* __restrict__ W) {
    if (blockIdx.x >= 1024) {
        // W -> bf16 conversion; also zero the violation counter
        int i = (blockIdx.x - 1024) * 256 + threadIdx.x;
        if (i == 0) g_viol = 0u;
        float4 v = ((const float4*)W)[i];
        short4 o;
        o.x = ((__hip_bfloat16_raw)__float2bfloat16(v.x)).x;
        o.y = ((__hip_bfloat16_raw)__float2bfloat16(v.y)).x;
        o.z = ((__hip_bfloat16_raw)__float2bfloat16(v.z)).x;
        o.w = ((__hip_bfloat16_raw)__float2bfloat16(v.w)).x;
        ((short4*)g_Wb)[i] = o;
        return;
    }
    int seg  = (int)((blockIdx.x * blockDim.x + threadIdx.x) >> 6);
    int lane = threadIdx.x & 63;
    if (seg >= Nq) return;
    int half = seg >> 11;
    int b    = seg & 2047;
    int baseRow = half * NROW + b * Cq;
    float invt = 1.f / attn_temp[0];

    float4 q4[3];
#pragma unroll
    for (int j = 0; j < 3; ++j) q4[j] = *(const float4*)(query + j * 256 + lane * 4);

    float4 v4[Cq][3];
    float s[Cq];
#pragma unroll
    for (int c = 0; c < Cq; ++c) {
        const float* zr = z + (size_t)(baseRow + c) * Dq;
        float acc = 0.f;
#pragma unroll
        for (int j = 0; j < 3; ++j) {
            float4 vz = *(const float4*)(zr + j * 256 + lane * 4);
            v4[c][j] = vz;
            acc += vz.x * q4[j].x + vz.y * q4[j].y + vz.z * q4[j].z + vz.w * q4[j].w;
        }
#pragma unroll
        for (int o = 32; o > 0; o >>= 1) acc += __shfl_xor(acc, o, 64);
        s[c] = acc * invt;
    }
    float m = s[0];
#pragma unroll
    for (int c = 1; c < Cq; ++c) m = fmaxf(m, s[c]);
    float e[Cq], denom = 0.f;
#pragma unroll
    for (int c = 0; c < Cq; ++c) { e[c] = expf(s[c] - m); denom += e[c]; }
    float inv = 1.f / (denom + 1e-8f);
#pragma unroll
    for (int j = 0; j < 3; ++j) {
        float4 acc = {0.f, 0.f, 0.f, 0.f};
#pragma unroll
        for (int c = 0; c < Cq; ++c) {
            acc.x += v4[c][j].x * e[c];
            acc.y += v4[c][j].y * e[c];
            acc.z += v4[c][j].z * e[c];
            acc.w += v4[c][j].w * e[c];
        }
        short4 o;
        o.x = ((__hip_bfloat16_raw)__float2bfloat16(acc.x * inv)).x;
        o.y = ((__hip_bfloat16_raw)__float2bfloat16(acc.y * inv)).x;
        o.z = ((__hip_bfloat16_raw)__float2bfloat16(acc.z * inv)).x;
        o.w = ((__hip_bfloat16_raw)__float2bfloat16(acc.w * inv)).x;
        *(short4*)((short*)g_pooledb + (size_t)seg * Dq + j * 256 + lane * 4) = o;
    }
}

// ---------- f = pooled @ W^T + b via bf16 MFMA (M=4096, N=768, K=768) ----------
__global__ __launch_bounds__(256) void fw_mfma_kernel(const float* __restrict__ bias) {
    __shared__ short lA[128 * 32];
    __shared__ short lB[128 * 32];
    const int bm = blockIdx.y * 128;
    const int bn = blockIdx.x * 128;

    const int tid  = threadIdx.x;
    const int wave = tid >> 6, lane = tid & 63;
    const int wr = wave >> 1, wc = wave & 1;

    const short* A = (const short*)g_pooledb;
    const short* Bt = (const short*)g_Wb;

    const int c0 = wave * 2, c1 = wave * 2 + 1;
    const int srow = lane >> 2;
    const int scol = (lane & 3) * 8;

    f32x4 acc[4][4];
#pragma unroll
    for (int m = 0; m < 4; ++m)
#pragma unroll
        for (int n = 0; n < 4; ++n) acc[m][n] = (f32x4){0.f, 0.f, 0.f, 0.f};

    for (int k0 = 0; k0 < Dq; k0 += 32) {
        GLDS16(A  + (size_t)(bm + c0 * 16 + srow) * Dq + k0 + scol, lA + c0 * 512);
        GLDS16(A  + (size_t)(bm + c1 * 16 + srow) * Dq + k0 + scol, lA + c1 * 512);
        GLDS16(Bt + (size_t)(bn + c0 * 16 + srow) * Dq + k0 + scol, lB + c0 * 512);
        GLDS16(Bt + (size_t)(bn + c1 * 16 + srow) * Dq + k0 + scol, lB + c1 * 512);
        __syncthreads();

        bf16x8 af[4], bfr[4];
#pragma unroll
        for (int m = 0; m < 4; ++m) {
            int row = wr * 64 + m * 16 + (lane & 15);
            af[m] = *(const bf16x8*)(lA + row * 32 + (lane >> 4) * 8);
        }
#pragma unroll
        for (int n = 0; n < 4; ++n) {
            int row = wc * 64 + n * 16 + (lane & 15);
            bfr[n] = *(const bf16x8*)(lB + row * 32 + (lane >> 4) * 8);
        }
#pragma unroll
        for (int m = 0; m < 4; ++m)
#pragma unroll
            for (int n = 0; n < 4; ++n)
                acc[m][n] = __builtin_amdgcn_mfma_f32_16x16x32_bf16(af[m], bfr[n], acc[m][n], 0, 0, 0);
        __syncthreads();
    }

#pragma unroll
    for (int m = 0; m < 4; ++m) {
        int rowb = bm + wr * 64 + m * 16 + (lane >> 4) * 4;
#pragma unroll
        for (int n = 0; n < 4; ++n) {
            int col = bn + wc * 64 + n * 16 + (lane & 15);
            float bc = bias[col];
#pragma unroll
            for (int j = 0; j < 4; ++j)
                g_f[(size_t)(rowb + j) * Dq + col] = acc[m][n][j] + bc;
        }
    }
}

// ---------- row-normalize -> bf16, one wave per row ----------
__global__ __launch_bounds__(256) void normalize_kernel() {
    int row  = (int)((blockIdx.x * blockDim.x + threadIdx.x) >> 6);
    int lane = threadIdx.x & 63;
    if (row >= Nq) return;
    float ss = 0.f;
    float v[Dq / 64];
#pragma unroll
    for (int j = 0; j < Dq / 64; ++j) { v[j] = g_f[(size_t)row * Dq + j * 64 + lane]; ss += v[j] * v[j]; }
#pragma unroll
    for (int o = 32; o > 0; o >>= 1) ss += __shfl_xor(ss, o, 64);
    float rn = 1.f / sqrtf(ss);
#pragma unroll
    for (int j = 0; j < Dq / 64; ++j)
        g_fb[(size_t)row * Dq + j * 64 + lane] = __float2bfloat16(v[j] * rn);
}

// ---------- sim = fb @ fb^T via bf16 MFMA -> fp16 store; epilogue counts sim>0.9 ----------
__global__ __launch_bounds__(256) void sim_mfma_kernel() {
    __shared__ short lA[128 * 32];
    __shared__ short lB[128 * 32];

    int t = blockIdx.x;
    int bi = 0, rem = t;
    while (rem >= (32 - bi)) { rem -= (32 - bi); ++bi; }
    int bj = bi + rem;
    int bm = bi * 128, bn = bj * 128;

    const int tid  = threadIdx.x;
    const int wave = tid >> 6, lane = tid & 63;
    const int wr = wave >> 1, wc = wave & 1;

    const short* fb = (const short*)g_fb;

    const int c0 = wave * 2, c1 = wave * 2 + 1;
    const int srow = lane >> 2;
    const int scol = (lane & 3) * 8;

    f32x4 acc[4][4];
#pragma unroll
    for (int m = 0; m < 4; ++m)
#pragma unroll
        for (int n = 0; n < 4; ++n) acc[m][n] = (f32x4){0.f, 0.f, 0.f, 0.f};

    for (int k0 = 0; k0 < Dq; k0 += 32) {
        GLDS16(fb + (size_t)(bm + c0 * 16 + srow) * Dq + k0 + scol, lA + c0 * 512);
        GLDS16(fb + (size_t)(bm + c1 * 16 + srow) * Dq + k0 + scol, lA + c1 * 512);
        GLDS16(fb + (size_t)(bn + c0 * 16 + srow) * Dq + k0 + scol, lB + c0 * 512);
        GLDS16(fb + (size_t)(bn + c1 * 16 + srow) * Dq + k0 + scol, lB + c1 * 512);
        __syncthreads();

        bf16x8 af[4], bfr[4];
#pragma unroll
        for (int m = 0; m < 4; ++m) {
            int row = wr * 64 + m * 16 + (lane & 15);
            af[m] = *(const bf16x8*)(lA + row * 32 + (lane >> 4) * 8);
        }
#pragma unroll
        for (int n = 0; n < 4; ++n) {
            int row = wc * 64 + n * 16 + (lane & 15);
            bfr[n] = *(const bf16x8*)(lB + row * 32 + (lane >> 4) * 8);
        }
#pragma unroll
        for (int m = 0; m < 4; ++m)
#pragma unroll
            for (int n = 0; n < 4; ++n)
                acc[m][n] = __builtin_amdgcn_mfma_f32_16x16x32_bf16(af[m], bfr[n], acc[m][n], 0, 0, 0);
        __syncthreads();
    }

    int vio = 0;
#pragma unroll
    for (int m = 0; m < 4; ++m) {
        int rowb = bm + wr * 64 + m * 16 + (lane >> 4) * 4;
#pragma unroll
        for (int n = 0; n < 4; ++n) {
            int col = bn + wc * 64 + n * 16 + (lane & 15);
#pragma unroll
            for (int j = 0; j < 4; ++j) {
                g_simh[(size_t)(rowb + j) * Nq + col] = (_Float16)acc[m][n][j];
                vio += (acc[m][n][j] > 0.9f) && ((((rowb + j) ^ col) & 2047) != 0);
            }
        }
    }
    if (bi != bj) {
        // mirror store: 4 consecutive rows along fastest dim -> 8B per lane;
        // lanes {l, l+16, l+32, l+48} fill one 32B run (L2 write-combines)
#pragma unroll
        for (int m = 0; m < 4; ++m) {
            int rowb = bm + wr * 64 + m * 16 + (lane >> 4) * 4;
#pragma unroll
            for (int n = 0; n < 4; ++n) {
                int col = bn + wc * 64 + n * 16 + (lane & 15);
                f16x4 h;
#pragma unroll
                for (int j = 0; j < 4; ++j) h[j] = (_Float16)acc[m][n][j];
                *(f16x4*)&g_simh[(size_t)col * Nq + rowb] = h;
            }
        }
        vio *= 2;   // mirrored elements violate identically
    }
#pragma unroll
    for (int o = 32; o > 0; o >>= 1) vio += __shfl_xor(vio, o, 64);
    if (lane == 0 && vio > 0) atomicAdd(&g_viol, (unsigned int)vio);
}

// ---------- per-row top-k logsumexp: one wave per row, ballot-popcount bisection ----------
__global__ __launch_bounds__(256) void lse_kernel() {
    const int row_id = (int)((blockIdx.x * blockDim.x + threadIdx.x) >> 6);  // 4 rows/block
    const int lane = threadIdx.x & 63;
    const _Float16* row = g_simh + (size_t)row_id * Nq;
    const int labi = row_id & 2047;
    const float invT = 1.0f / TEMPq;

    long long total = (long long)Nq * 4094LL - (long long)g_viol;
    int k = (int)(total / 8192LL);
    if (k < 1) k = 1;

    // 64 values/lane via 8x 16B fp16 loads; unsafe -> sentinel -2
    float v[64];
    float mx = -1e30f, mn = 1e30f;
    int cnt = 0;
#pragma unroll
    for (int q = 0; q < 8; ++q) {
        int j0 = q * 512 + lane * 8;
        f16x8 x8 = *(const f16x8*)(row + j0);
#pragma unroll
        for (int s = 0; s < 8; ++s) {
            int jj = q * 8 + s;
            int j  = j0 + s;
            float xv = (float)x8[s];
            bool sf = (xv <= 0.9f) && (((j ^ labi) & 2047) != 0);
            float val = sf ? xv : -2.0f;
            v[jj] = val;
            mx = fmaxf(mx, val);
            mn = fminf(mn, sf ? xv : 2.0f);
            cnt += (int)__popcll(__ballot(sf));
        }
    }
#pragma unroll
    for (int o = 32; o > 0; o >>= 1) {
        mx = fmaxf(mx, __shfl_xor(mx, o, 64));
        mn = fminf(mn, __shfl_xor(mn, o, 64));
    }

    const float pos = (float)row[(row_id + Bq) & (Nq - 1)];
    const float mxs = (cnt > 0) ? mx : -10.0f;
    const float ml  = fmaxf(pos, mxs) * invT;

    float lo = mn - 1e-3f, hi = mx;
    int c_hi = 0;
    const bool need = (cnt > k);
    if (need) {
        for (int it = 0; it < 12; ++it) {
            float mid = 0.5f * (lo + hi);
            int c = 0;
#pragma unroll
            for (int jj = 0; jj < 64; ++jj)
                c += (int)__popcll(__ballot(v[jj] > mid));
            if (c > k) lo = mid; else { hi = mid; c_hi = c; }
        }
    }

    float shi = 0.f, st = 0.f; int nt = 0;
#pragma unroll
    for (int jj = 0; jj < 64; ++jj) {
        float x = v[jj];
        float ev = __expf(x * invT - ml);
        if (!need)       { if (x > -1.5f) shi += ev; }
        else if (x > hi) { shi += ev; }
        else if (x > lo) { st += ev; nt++; }
    }
#pragma unroll
    for (int o = 32; o > 0; o >>= 1) {
        shi += __shfl_xor(shi, o, 64);
        st  += __shfl_xor(st,  o, 64);
        nt  += __shfl_xor(nt,  o, 64);
    }
    if (lane == 0) {
        float S = __expf(pos * invT - ml) + shi;
        if (need && c_hi < k && nt > 0)
            S += st * (float)(k - c_hi) / (float)nt;
        g_rowloss[row_id] = (logf(S) + ml) - pos * invT;
    }
}

// ---------- final mean ----------
__global__ __launch_bounds__(256) void loss_kernel(float* __restrict__ out) {
    float s = 0.f;
    for (int i = threadIdx.x; i < Nq; i += 256) s += g_rowloss[i];
    __shared__ float sm[256];
    sm[threadIdx.x] = s; __syncthreads();
    for (int o = 128; o > 0; o >>= 1) {
        if (threadIdx.x < o) sm[threadIdx.x] += sm[threadIdx.x + o];
        __syncthreads();
    }
    if (threadIdx.x == 0) out[0] = sm[0] / (float)Nq;
}

extern "C" void kernel_launch(void* const* d_in, const int* in_sizes, int n_in,
                              void* d_out, int out_size, void* d_ws, size_t ws_size,
                              hipStream_t stream) {
    const float* z         = (const float*)d_in[0];
    const float* query     = (const float*)d_in[3];
    const float* attn_temp = (const float*)d_in[4];
    const float* W         = (const float*)d_in[5];
    const float* bias      = (const float*)d_in[6];
    float* out = (float*)d_out;

    prep_kernel<<<1024 + (Dq * Dq / 4) / 256, 256, 0, stream>>>(z, query, attn_temp, W);
    fw_mfma_kernel<<<dim3(Dq / 128, Nq / 128), 256, 0, stream>>>(bias);
    normalize_kernel<<<Nq / 4, 256, 0, stream>>>();
    sim_mfma_kernel<<<(32 * 33) / 2, 256, 0, stream>>>();
    lse_kernel<<<Nq / 4, 256, 0, stream>>>();
    loss_kernel<<<1, 256, 0, stream>>>(out);
}

// Round 8
// 116.229 us; speedup vs baseline: 4.6389x; 1.0433x over previous
//
#include <hip/hip_runtime.h>
#include <hip/hip_bf16.h>
#include <math.h>

#define Bq   2048
#define Cq   8
#define Dq   768
#define NROW 16384      // B*C per half
#define NTOT 32768      // 2*B*C
#define Nq   4096       // 2*B rows of f
#define TEMPq 0.07f
#define NKC  96         // 768/8 k-chunks of 8 bf16 (16 B)

typedef __attribute__((ext_vector_type(8))) short bf16x8;
typedef __attribute__((ext_vector_type(4))) float f32x4;
typedef __attribute__((ext_vector_type(8))) _Float16 f16x8;

// persistent device scratch (fully overwritten every call -> deterministic)
__device__ __hip_bfloat16 g_pooledb[(size_t)Nq * Dq];
__device__ __hip_bfloat16 g_Wb[(size_t)Dq * Dq];
__device__ float          g_f[(size_t)Nq * Dq];
__device__ short          g_fbt[(size_t)NKC * Nq * 8];   // [kc][row][8 bf16] chunk-transposed
__device__ _Float16       g_simh[(size_t)Nq * Nq];
__device__ unsigned int   g_viol;
__device__ float          g_rowloss[Nq];

#define GLDS16(src, dst) __builtin_amdgcn_global_load_lds( \
    (const __attribute__((address_space(1))) void*)(src),  \
    (__attribute__((address_space(3))) void*)(dst), 16, 0, 0)

// ---------- merged: [blocks 0..1023] fused pool, [1024..1599] W->bf16 ----------
__global__ __launch_bounds__(256) void prep_kernel(const float* __restrict__ z,
                                                   const float* __restrict__ query,
                                                   const float* __restrict__ attn_temp,
                                                   const float* __restrict__ W) {
    if (blockIdx.x >= 1024) {
        int i = (blockIdx.x - 1024) * 256 + threadIdx.x;
        if (i == 0) g_viol = 0u;
        float4 v = ((const float4*)W)[i];
        short4 o;
        o.x = ((__hip_bfloat16_raw)__float2bfloat16(v.x)).x;
        o.y = ((__hip_bfloat16_raw)__float2bfloat16(v.y)).x;
        o.z = ((__hip_bfloat16_raw)__float2bfloat16(v.z)).x;
        o.w = ((__hip_bfloat16_raw)__float2bfloat16(v.w)).x;
        ((short4*)g_Wb)[i] = o;
        return;
    }
    int seg  = (int)((blockIdx.x * blockDim.x + threadIdx.x) >> 6);
    int lane = threadIdx.x & 63;
    if (seg >= Nq) return;
    int half = seg >> 11;
    int b    = seg & 2047;
    int baseRow = half * NROW + b * Cq;
    float invt = 1.f / attn_temp[0];

    float4 q4[3];
#pragma unroll
    for (int j = 0; j < 3; ++j) q4[j] = *(const float4*)(query + j * 256 + lane * 4);

    float4 v4[Cq][3];
    float s[Cq];
#pragma unroll
    for (int c = 0; c < Cq; ++c) {
        const float* zr = z + (size_t)(baseRow + c) * Dq;
        float acc = 0.f;
#pragma unroll
        for (int j = 0; j < 3; ++j) {
            float4 vz = *(const float4*)(zr + j * 256 + lane * 4);
            v4[c][j] = vz;
            acc += vz.x * q4[j].x + vz.y * q4[j].y + vz.z * q4[j].z + vz.w * q4[j].w;
        }
#pragma unroll
        for (int o = 32; o > 0; o >>= 1) acc += __shfl_xor(acc, o, 64);
        s[c] = acc * invt;
    }
    float m = s[0];
#pragma unroll
    for (int c = 1; c < Cq; ++c) m = fmaxf(m, s[c]);
    float e[Cq], denom = 0.f;
#pragma unroll
    for (int c = 0; c < Cq; ++c) { e[c] = expf(s[c] - m); denom += e[c]; }
    float inv = 1.f / (denom + 1e-8f);
#pragma unroll
    for (int j = 0; j < 3; ++j) {
        float4 acc = {0.f, 0.f, 0.f, 0.f};
#pragma unroll
        for (int c = 0; c < Cq; ++c) {
            acc.x += v4[c][j].x * e[c];
            acc.y += v4[c][j].y * e[c];
            acc.z += v4[c][j].z * e[c];
            acc.w += v4[c][j].w * e[c];
        }
        short4 o;
        o.x = ((__hip_bfloat16_raw)__float2bfloat16(acc.x * inv)).x;
        o.y = ((__hip_bfloat16_raw)__float2bfloat16(acc.y * inv)).x;
        o.z = ((__hip_bfloat16_raw)__float2bfloat16(acc.z * inv)).x;
        o.w = ((__hip_bfloat16_raw)__float2bfloat16(acc.w * inv)).x;
        *(short4*)((short*)g_pooledb + (size_t)seg * Dq + j * 256 + lane * 4) = o;
    }
}

// ---------- f = pooled @ W^T + b via bf16 MFMA (M=4096, N=768, K=768) ----------
__global__ __launch_bounds__(256) void fw_mfma_kernel(const float* __restrict__ bias) {
    __shared__ short lA[128 * 32];
    __shared__ short lB[128 * 32];
    const int bm = blockIdx.y * 128;
    const int bn = blockIdx.x * 128;

    const int tid  = threadIdx.x;
    const int wave = tid >> 6, lane = tid & 63;
    const int wr = wave >> 1, wc = wave & 1;

    const short* A = (const short*)g_pooledb;
    const short* Bt = (const short*)g_Wb;

    const int c0 = wave * 2, c1 = wave * 2 + 1;
    const int srow = lane >> 2;
    const int scol = (lane & 3) * 8;

    f32x4 acc[4][4];
#pragma unroll
    for (int m = 0; m < 4; ++m)
#pragma unroll
        for (int n = 0; n < 4; ++n) acc[m][n] = (f32x4){0.f, 0.f, 0.f, 0.f};

    for (int k0 = 0; k0 < Dq; k0 += 32) {
        GLDS16(A  + (size_t)(bm + c0 * 16 + srow) * Dq + k0 + scol, lA + c0 * 512);
        GLDS16(A  + (size_t)(bm + c1 * 16 + srow) * Dq + k0 + scol, lA + c1 * 512);
        GLDS16(Bt + (size_t)(bn + c0 * 16 + srow) * Dq + k0 + scol, lB + c0 * 512);
        GLDS16(Bt + (size_t)(bn + c1 * 16 + srow) * Dq + k0 + scol, lB + c1 * 512);
        __syncthreads();

        bf16x8 af[4], bfr[4];
#pragma unroll
        for (int m = 0; m < 4; ++m) {
            int row = wr * 64 + m * 16 + (lane & 15);
            af[m] = *(const bf16x8*)(lA + row * 32 + (lane >> 4) * 8);
        }
#pragma unroll
        for (int n = 0; n < 4; ++n) {
            int row = wc * 64 + n * 16 + (lane & 15);
            bfr[n] = *(const bf16x8*)(lB + row * 32 + (lane >> 4) * 8);
        }
#pragma unroll
        for (int m = 0; m < 4; ++m)
#pragma unroll
            for (int n = 0; n < 4; ++n)
                acc[m][n] = __builtin_amdgcn_mfma_f32_16x16x32_bf16(af[m], bfr[n], acc[m][n], 0, 0, 0);
        __syncthreads();
    }

#pragma unroll
    for (int m = 0; m < 4; ++m) {
        int rowb = bm + wr * 64 + m * 16 + (lane >> 4) * 4;
#pragma unroll
        for (int n = 0; n < 4; ++n) {
            int col = bn + wc * 64 + n * 16 + (lane & 15);
            float bc = bias[col];
#pragma unroll
            for (int j = 0; j < 4; ++j)
                g_f[(size_t)(rowb + j) * Dq + col] = acc[m][n][j] + bc;
        }
    }
}

// ---------- row-normalize -> bf16, chunk-transposed store. 16 rows/block ----------
__global__ __launch_bounds__(256) void normalize_kernel() {
    __shared__ short rowbuf[16][776];   // 776 = 768 + 8 pad (keeps 16B align, breaks worst banks)
    const int tid = threadIdx.x;
    const int wave = tid >> 6, lane = tid & 63;
    const int r0 = blockIdx.x * 16;

    for (int rr = wave; rr < 16; rr += 4) {
        int row = r0 + rr;
        float v[12];
        float ss = 0.f;
#pragma unroll
        for (int j = 0; j < 12; ++j) { v[j] = g_f[(size_t)row * Dq + j * 64 + lane]; ss += v[j] * v[j]; }
#pragma unroll
        for (int o = 32; o > 0; o >>= 1) ss += __shfl_xor(ss, o, 64);
        float rn = 1.f / sqrtf(ss);
#pragma unroll
        for (int j = 0; j < 12; ++j)
            rowbuf[rr][j * 64 + lane] = ((__hip_bfloat16_raw)__float2bfloat16(v[j] * rn)).x;
    }
    __syncthreads();
    // store 96 chunks x 16 rows: idx -> ch = idx>>4, r = idx&15 (lanes 0-15 contiguous rows)
#pragma unroll
    for (int i = 0; i < 6; ++i) {
        int idx = i * 256 + tid;
        int ch = idx >> 4;
        int r  = idx & 15;
        bf16x8 val = *(const bf16x8*)&rowbuf[r][ch * 8];
        *(bf16x8*)&g_fbt[((size_t)ch * Nq + r0 + r) * 8] = val;
    }
}

// ---------- sim = fb @ fb^T : 256^2 tile, 8 waves, BK=64, dbuf + counted vmcnt ----------
// LDS chunk layout: A chunk(kc8 0..7, r 0..255) at (buf*2048 + kc8*256 + r)*16B -> frag
// ds_read_b128 runs over consecutive chunks => conflict-free by construction.
#define STAGE_SIM(b, kt_) do {                                                          \
    _Pragma("unroll")                                                                   \
    for (int i = 0; i < 4; ++i) {                                                       \
        GLDS16(fbt + ((size_t)((kt_) * 8 + wave) * Nq + bm + i * 64 + lane) * 8,        \
               As + ((b) * 2048 + wave * 256 + i * 64) * 8);                            \
        GLDS16(fbt + ((size_t)((kt_) * 8 + wave) * Nq + bn + i * 64 + lane) * 8,        \
               Bs + ((b) * 2048 + wave * 256 + i * 64) * 8);                            \
    }                                                                                   \
} while (0)

__global__ __launch_bounds__(512) void sim_mfma_kernel() {
    extern __shared__ short smem[];          // 128 KiB: A 2x2048 chunks, B 2x2048 chunks
    short* As = smem;
    short* Bs = smem + 32768;

    const int tid  = threadIdx.x;
    const int wave = tid >> 6, lane = tid & 63;
    const int wm = wave >> 2, wn = wave & 3;       // 2 x 4 wave grid; per-wave C: 128 x 64
    const int bm = blockIdx.y * 256, bn = blockIdx.x * 256;
    const short* fbt = g_fbt;

    f32x4 acc[8][4];
#pragma unroll
    for (int mi = 0; mi < 8; ++mi)
#pragma unroll
        for (int ni = 0; ni < 4; ++ni) acc[mi][ni] = (f32x4){0.f, 0.f, 0.f, 0.f};

    STAGE_SIM(0, 0);

#pragma unroll 1
    for (int kt = 0; kt < 12; ++kt) {
        const int cur = kt & 1;
        if (kt < 11) {
            STAGE_SIM(cur ^ 1, kt + 1);
            asm volatile("s_waitcnt vmcnt(8)" ::: "memory");   // own 8 loads of tile kt done
        } else {
            asm volatile("s_waitcnt vmcnt(0)" ::: "memory");
        }
        __builtin_amdgcn_s_barrier();                           // all waves' tile-kt loads landed
        __builtin_amdgcn_sched_barrier(0);

#pragma unroll
        for (int ks = 0; ks < 2; ++ks) {
            bf16x8 af[8], bfr[4];
            const int kc = (ks * 4 + (lane >> 4)) * 256;
#pragma unroll
            for (int mi = 0; mi < 8; ++mi)
                af[mi] = *(const bf16x8*)(As + (cur * 2048 + kc + wm * 128 + mi * 16 + (lane & 15)) * 8);
#pragma unroll
            for (int ni = 0; ni < 4; ++ni)
                bfr[ni] = *(const bf16x8*)(Bs + (cur * 2048 + kc + wn * 64 + ni * 16 + (lane & 15)) * 8);
            __builtin_amdgcn_s_setprio(1);
#pragma unroll
            for (int mi = 0; mi < 8; ++mi)
#pragma unroll
                for (int ni = 0; ni < 4; ++ni)
                    acc[mi][ni] = __builtin_amdgcn_mfma_f32_16x16x32_bf16(af[mi], bfr[ni], acc[mi][ni], 0, 0, 0);
            __builtin_amdgcn_s_setprio(0);
        }
        __builtin_amdgcn_sched_barrier(0);
        __builtin_amdgcn_s_barrier();                           // reads done before buffer reuse
    }

    // epilogue: fp16 store (full matrix, no mirror) + violation count
    int vio = 0;
#pragma unroll
    for (int mi = 0; mi < 8; ++mi) {
        int rowb = bm + wm * 128 + mi * 16 + (lane >> 4) * 4;
#pragma unroll
        for (int ni = 0; ni < 4; ++ni) {
            int col = bn + wn * 64 + ni * 16 + (lane & 15);
#pragma unroll
            for (int j = 0; j < 4; ++j) {
                float x = acc[mi][ni][j];
                g_simh[(size_t)(rowb + j) * Nq + col] = (_Float16)x;
                vio += (x > 0.9f) && ((((rowb + j) ^ col) & 2047) != 0);
            }
        }
    }
#pragma unroll
    for (int o = 32; o > 0; o >>= 1) vio += __shfl_xor(vio, o, 64);
    if (lane == 0 && vio > 0) atomicAdd(&g_viol, (unsigned int)vio);
}

// ---------- per-row top-k logsumexp: one wave per row, ballot-popcount bisection ----------
__global__ __launch_bounds__(256) void lse_kernel() {
    const int row_id = (int)((blockIdx.x * blockDim.x + threadIdx.x) >> 6);
    const int lane = threadIdx.x & 63;
    const _Float16* row = g_simh + (size_t)row_id * Nq;
    const int labi = row_id & 2047;
    const float invT = 1.0f / TEMPq;

    long long total = (long long)Nq * 4094LL - (long long)g_viol;
    int k = (int)(total / 8192LL);
    if (k < 1) k = 1;

    float v[64];
    float mx = -1e30f, mn = 1e30f;
    int cnt = 0;
#pragma unroll
    for (int q = 0; q < 8; ++q) {
        int j0 = q * 512 + lane * 8;
        f16x8 x8 = *(const f16x8*)(row + j0);
#pragma unroll
        for (int s = 0; s < 8; ++s) {
            int jj = q * 8 + s;
            int j  = j0 + s;
            float xv = (float)x8[s];
            bool sf = (xv <= 0.9f) && (((j ^ labi) & 2047) != 0);
            float val = sf ? xv : -2.0f;
            v[jj] = val;
            mx = fmaxf(mx, val);
            mn = fminf(mn, sf ? xv : 2.0f);
            cnt += (int)__popcll(__ballot(sf));
        }
    }
#pragma unroll
    for (int o = 32; o > 0; o >>= 1) {
        mx = fmaxf(mx, __shfl_xor(mx, o, 64));
        mn = fminf(mn, __shfl_xor(mn, o, 64));
    }

    const float pos = (float)row[(row_id + Bq) & (Nq - 1)];
    const float mxs = (cnt > 0) ? mx : -10.0f;
    const float ml  = fmaxf(pos, mxs) * invT;

    float lo = mn - 1e-3f, hi = mx;
    int c_hi = 0;
    const bool need = (cnt > k);
    if (need) {
        for (int it = 0; it < 12; ++it) {
            float mid = 0.5f * (lo + hi);
            int c = 0;
#pragma unroll
            for (int jj = 0; jj < 64; ++jj)
                c += (int)__popcll(__ballot(v[jj] > mid));
            if (c > k) lo = mid; else { hi = mid; c_hi = c; }
        }
    }

    float shi = 0.f, st = 0.f; int nt = 0;
#pragma unroll
    for (int jj = 0; jj < 64; ++jj) {
        float x = v[jj];
        float ev = __expf(x * invT - ml);
        if (!need)       { if (x > -1.5f) shi += ev; }
        else if (x > hi) { shi += ev; }
        else if (x > lo) { st += ev; nt++; }
    }
#pragma unroll
    for (int o = 32; o > 0; o >>= 1) {
        shi += __shfl_xor(shi, o, 64);
        st  += __shfl_xor(st,  o, 64);
        nt  += __shfl_xor(nt,  o, 64);
    }
    if (lane == 0) {
        float S = __expf(pos * invT - ml) + shi;
        if (need && c_hi < k && nt > 0)
            S += st * (float)(k - c_hi) / (float)nt;
        g_rowloss[row_id] = (logf(S) + ml) - pos * invT;
    }
}

// ---------- final mean ----------
__global__ __launch_bounds__(256) void loss_kernel(float* __restrict__ out) {
    float s = 0.f;
    for (int i = threadIdx.x; i < Nq; i += 256) s += g_rowloss[i];
    __shared__ float sm[256];
    sm[threadIdx.x] = s; __syncthreads();
    for (int o = 128; o > 0; o >>= 1) {
        if (threadIdx.x < o) sm[threadIdx.x] += sm[threadIdx.x + o];
        __syncthreads();
    }
    if (threadIdx.x == 0) out[0] = sm[0] / (float)Nq;
}

extern "C" void kernel_launch(void* const* d_in, const int* in_sizes, int n_in,
                              void* d_out, int out_size, void* d_ws, size_t ws_size,
                              hipStream_t stream) {
    const float* z         = (const float*)d_in[0];
    const float* query     = (const float*)d_in[3];
    const float* attn_temp = (const float*)d_in[4];
    const float* W         = (const float*)d_in[5];
    const float* bias      = (const float*)d_in[6];
    float* out = (float*)d_out;

    prep_kernel<<<1024 + (Dq * Dq / 4) / 256, 256, 0, stream>>>(z, query, attn_temp, W);
    fw_mfma_kernel<<<dim3(Dq / 128, Nq / 128), 256, 0, stream>>>(bias);
    normalize_kernel<<<Nq / 16, 256, 0, stream>>>();
    sim_mfma_kernel<<<dim3(16, 16), 512, 131072, stream>>>();
    lse_kernel<<<Nq / 4, 256, 0, stream>>>();
    loss_kernel<<<1, 256, 0, stream>>>(out);
}